// Round 1
// baseline (322.992 us; speedup 1.0000x reference)
//
#include <hip/hip_runtime.h>
#include <math.h>

typedef unsigned short u16;
typedef unsigned int u32;

using f32x4 = __attribute__((ext_vector_type(4))) float;
using s16x8 = __attribute__((ext_vector_type(8))) short;
using u32x4 = __attribute__((ext_vector_type(4))) u32;

#define DEVI static __device__ __forceinline__

// ---- problem constants ----
#define BB 16
#define TT 512
#define TS 512
#define HH 1024
#define OO 1024

// split fp32 -> bf16 hi (truncated) + bf16 lo (truncated residual).
// x = hi + lo + eps, |eps| <= 2^-16 |x|. hi-part subtraction is exact.
DEVI void split1(float x, u32& hb, u32& lb) {
    u32 xb = __float_as_uint(x);
    float hf = __uint_as_float(xb & 0xffff0000u);
    hb = xb >> 16;
    lb = __float_as_uint(x - hf) >> 16;
}

// lens[b] = count of non-zero source tokens (prefix-mask length), matches ref
__global__ void lens_kernel(const int* __restrict__ src, int* __restrict__ lens) {
    int b = blockIdx.x;
    int v = (src[b * TS + (int)threadIdx.x] != 0) ? 1 : 0;
    unsigned long long m = __ballot(v);
    __shared__ int part[8];
    if ((threadIdx.x & 63) == 0) part[threadIdx.x >> 6] = __popcll(m);
    __syncthreads();
    if (threadIdx.x == 0) {
        int s = 0;
#pragma unroll
        for (int i = 0; i < 8; ++i) s += part[i];
        lens[b] = s;
    }
}

// transpose fp32 src[R][C] (row-major) -> split bf16 hi/lo out[C][R]; grid.z = batch
__global__ void transpose_split_kernel(const float* __restrict__ src,
                                       u16* __restrict__ dhi, u16* __restrict__ dlo,
                                       int R, int C) {
    __shared__ float tile[32][33];
    long boff = (long)blockIdx.z * R * C;
    src += boff; dhi += boff; dlo += boff;
    int c0 = blockIdx.x * 32, r0 = blockIdx.y * 32;
    int tx = threadIdx.x, ty = threadIdx.y;
#pragma unroll
    for (int i = 0; i < 32; i += 8)
        tile[ty + i][tx] = src[(long)(r0 + ty + i) * C + (c0 + tx)];
    __syncthreads();
#pragma unroll
    for (int i = 0; i < 32; i += 8) {
        u32 hb, lb;
        split1(tile[tx][ty + i], hb, lb);
        long o = (long)(c0 + ty + i) * R + (r0 + tx);
        dhi[o] = (u16)hb;
        dlo[o] = (u16)lb;
    }
}

// in-place masked softmax on score [B*TT][TS], one wave per row.
// Matches ref: rowmax over FULL row, exp, multiply by prefix mask, normalize.
__global__ void softmax_mask_kernel(float* __restrict__ score, const int* __restrict__ lens) {
    long row = blockIdx.x;
    int len = lens[blockIdx.x >> 9];  // TT = 512
    float* p = score + row * TS;
    int lane = threadIdx.x;
    float4 v0 = *(const float4*)(p + 4 * lane);
    float4 v1 = *(const float4*)(p + TS / 2 + 4 * lane);
    float f[8] = {v0.x, v0.y, v0.z, v0.w, v1.x, v1.y, v1.z, v1.w};
    float m = f[0];
#pragma unroll
    for (int i = 1; i < 8; ++i) m = fmaxf(m, f[i]);
#pragma unroll
    for (int o = 32; o > 0; o >>= 1) m = fmaxf(m, __shfl_xor(m, o));
    float e[8];
    float sum = 0.f;
#pragma unroll
    for (int i = 0; i < 8; ++i) {
        int s = (i < 4) ? (4 * lane + i) : (TS / 2 + 4 * lane + (i - 4));
        e[i] = (s < len) ? expf(f[i] - m) : 0.f;
        sum += e[i];
    }
#pragma unroll
    for (int o = 32; o > 0; o >>= 1) sum += __shfl_xor(sum, o);
    float inv = 1.0f / sum;
    v0.x = e[0] * inv; v0.y = e[1] * inv; v0.z = e[2] * inv; v0.w = e[3] * inv;
    v1.x = e[4] * inv; v1.y = e[5] * inv; v1.z = e[6] * inv; v1.w = e[7] * inv;
    *(float4*)(p + 4 * lane) = v0;
    *(float4*)(p + TS / 2 + 4 * lane) = v1;
}

// C[m][n] = sum_k A[m][k] * Bt[n][k].
// A is fp32, split to bf16 hi/lo during LDS staging. Bt is pre-split bf16 hi/lo,
// row-major [n][k]. 3-MFMA double-bf16 => ~fp32 accuracy.
// EPI: 0 = fp32 store, 1 = split bf16 hi/lo store, 2 = tanh(x + bias[col]) store.
// CONCAT: A-operand is [A | A2] along k, each half row-stride HH (G4).
// Non-concat lda == K for every instance here.
template <int EPI, bool CONCAT>
__global__ __launch_bounds__(256, 2)
void gemm_split(const float* __restrict__ A, const float* __restrict__ A2,
                const u16* __restrict__ Bhi, const u16* __restrict__ Blo,
                float* __restrict__ C, u16* __restrict__ Chi, u16* __restrict__ Clo,
                const float* __restrict__ bias,
                int M, int N, int K,
                long sA, long sB, long sC) {
    int bz = blockIdx.z;
    A += (long)bz * sA;
    Bhi += (long)bz * sB;
    Blo += (long)bz * sB;

    int n0 = blockIdx.x * 128;
    int m0 = blockIdx.y * 128;

    // +8 pad: ds_read_b128 fragment reads spread over all 32 banks (2-way = free)
    __shared__ u16 Ah[128][40];
    __shared__ u16 Al[128][40];
    __shared__ u16 Bh[128][40];
    __shared__ u16 Bl[128][40];

    int tid = threadIdx.x;
    int lane = tid & 63;
    int wave = tid >> 6;
    int wm = (wave >> 1) * 64;  // wave output sub-tile origin
    int wn = (wave & 1) * 64;

    f32x4 acc[4][4];
#pragma unroll
    for (int i = 0; i < 4; ++i)
#pragma unroll
        for (int j = 0; j < 4; ++j) acc[i][j] = (f32x4){0.f, 0.f, 0.f, 0.f};

    int r = tid >> 1;           // staging row 0..127
    int hf = (tid & 1) * 16;    // k-offset 0/16 within the 32-wide K step

    int fr = lane & 15;         // fragment row/col within 16
    int kb = (lane >> 4) * 8;   // fragment k-offset (8 contiguous bf16)

    for (int k0 = 0; k0 < K; k0 += 32) {
        __syncthreads();
        // ---- stage A: 128x32 fp32 -> split bf16 hi/lo in LDS ----
        const float* asrc;
        if (CONCAT) {
            int kk = k0 + hf;
            asrc = (kk >= HH) ? (A2 + (long)(m0 + r) * HH + (kk - HH))
                              : (A + (long)(m0 + r) * HH + kk);
        } else {
            asrc = A + (long)(m0 + r) * K + (k0 + hf);
        }
        float4 av0 = *(const float4*)(asrc + 0);
        float4 av1 = *(const float4*)(asrc + 4);
        float4 av2 = *(const float4*)(asrc + 8);
        float4 av3 = *(const float4*)(asrc + 12);
        float fv[16] = {av0.x, av0.y, av0.z, av0.w, av1.x, av1.y, av1.z, av1.w,
                        av2.x, av2.y, av2.z, av2.w, av3.x, av3.y, av3.z, av3.w};
        u32 hb[16], lb[16];
#pragma unroll
        for (int i = 0; i < 16; ++i) split1(fv[i], hb[i], lb[i]);
        u32x4 ah0 = {hb[0] | (hb[1] << 16), hb[2] | (hb[3] << 16),
                     hb[4] | (hb[5] << 16), hb[6] | (hb[7] << 16)};
        u32x4 ah1 = {hb[8] | (hb[9] << 16), hb[10] | (hb[11] << 16),
                     hb[12] | (hb[13] << 16), hb[14] | (hb[15] << 16)};
        u32x4 al0 = {lb[0] | (lb[1] << 16), lb[2] | (lb[3] << 16),
                     lb[4] | (lb[5] << 16), lb[6] | (lb[7] << 16)};
        u32x4 al1 = {lb[8] | (lb[9] << 16), lb[10] | (lb[11] << 16),
                     lb[12] | (lb[13] << 16), lb[14] | (lb[15] << 16)};
        *(u32x4*)&Ah[r][hf] = ah0;
        *(u32x4*)&Ah[r][hf + 8] = ah1;
        *(u32x4*)&Al[r][hf] = al0;
        *(u32x4*)&Al[r][hf + 8] = al1;

        // ---- stage B: 128x32 pre-split bf16 hi/lo, straight copy ----
        const u16* bh = Bhi + (long)(n0 + r) * K + (k0 + hf);
        const u16* bl = Blo + (long)(n0 + r) * K + (k0 + hf);
        *(u32x4*)&Bh[r][hf] = *(const u32x4*)bh;
        *(u32x4*)&Bh[r][hf + 8] = *(const u32x4*)(bh + 8);
        *(u32x4*)&Bl[r][hf] = *(const u32x4*)bl;
        *(u32x4*)&Bl[r][hf + 8] = *(const u32x4*)(bl + 8);

        __syncthreads();

        // ---- fragments + 3-term MFMA ----
        s16x8 afh[4], afl[4], bfh[4], bfl[4];
#pragma unroll
        for (int i = 0; i < 4; ++i) {
            afh[i] = *(const s16x8*)&Ah[wm + i * 16 + fr][kb];
            afl[i] = *(const s16x8*)&Al[wm + i * 16 + fr][kb];
            bfh[i] = *(const s16x8*)&Bh[wn + i * 16 + fr][kb];
            bfl[i] = *(const s16x8*)&Bl[wn + i * 16 + fr][kb];
        }
#pragma unroll
        for (int i = 0; i < 4; ++i)
#pragma unroll
            for (int j = 0; j < 4; ++j) {
                acc[i][j] = __builtin_amdgcn_mfma_f32_16x16x32_bf16(afh[i], bfh[j], acc[i][j], 0, 0, 0);
                acc[i][j] = __builtin_amdgcn_mfma_f32_16x16x32_bf16(afl[i], bfh[j], acc[i][j], 0, 0, 0);
                acc[i][j] = __builtin_amdgcn_mfma_f32_16x16x32_bf16(afh[i], bfl[j], acc[i][j], 0, 0, 0);
            }
    }

    // ---- epilogue: C/D layout col = lane&15, row = (lane>>4)*4 + reg ----
    int fq = (lane >> 4) * 4;
#pragma unroll
    for (int i = 0; i < 4; ++i)
#pragma unroll
        for (int j = 0; j < 4; ++j)
#pragma unroll
            for (int g = 0; g < 4; ++g) {
                int row = m0 + wm + i * 16 + fq + g;
                int col = n0 + wn + j * 16 + fr;
                long idx = (long)bz * sC + (long)row * N + col;
                float v = acc[i][j][g];
                if constexpr (EPI == 0) {
                    C[idx] = v;
                } else if constexpr (EPI == 1) {
                    u32 h2, l2;
                    split1(v, h2, l2);
                    Chi[idx] = (u16)h2;
                    Clo[idx] = (u16)l2;
                } else {
                    C[idx] = tanhf(v + bias[col]);
                }
            }
}

extern "C" void kernel_launch(void* const* d_in, const int* in_sizes, int n_in,
                              void* d_out, int out_size, void* d_ws, size_t ws_size,
                              hipStream_t stream) {
    const float* ht = (const float*)d_in[0];
    const float* hs = (const float*)d_in[1];
    const int* source = (const int*)d_in[2];
    const float* Wa = (const float*)d_in[3];
    const float* Wc = (const float*)d_in[4];
    const float* bias = (const float*)d_in[5];
    float* out = (float*)d_out;

    char* w = (char*)d_ws;
    size_t off = 0;
    auto alloc = [&](size_t bytes) -> void* {
        void* p = w + off;
        off += (bytes + 255) & ~(size_t)255;
        return p;
    };
    int* lens = (int*)alloc(64);
    u16* keysHi = (u16*)alloc((size_t)BB * TS * HH * 2);  // 16.78 MB
    u16* keysLo = (u16*)alloc((size_t)BB * TS * HH * 2);
    float* score = (float*)alloc((size_t)BB * TT * TS * 4);  // 16.78 MB
    u16* hsTHi = (u16*)alloc((size_t)BB * HH * TS * 2);
    u16* hsTLo = (u16*)alloc((size_t)BB * HH * TS * 2);
    u16* WaTHi = (u16*)alloc((size_t)HH * HH * 2);
    u16* WaTLo = (u16*)alloc((size_t)HH * HH * 2);
    u16* WcTHi = (u16*)alloc((size_t)2 * HH * OO * 2);
    u16* WcTLo = (u16*)alloc((size_t)2 * HH * OO * 2);
    // c [B*TT][HH] fp32 (33.55 MB) overlays keysHi+keysLo (dead after G2; exact fit)
    float* cbuf = (float*)keysHi;

    // pre-passes
    lens_kernel<<<BB, TS, 0, stream>>>(source, lens);
    transpose_split_kernel<<<dim3(HH / 32, HH / 32, 1), dim3(32, 8), 0, stream>>>(
        Wa, WaTHi, WaTLo, HH, HH);
    transpose_split_kernel<<<dim3(OO / 32, 2 * HH / 32, 1), dim3(32, 8), 0, stream>>>(
        Wc, WcTHi, WcTLo, 2 * HH, OO);
    transpose_split_kernel<<<dim3(HH / 32, TS / 32, BB), dim3(32, 8), 0, stream>>>(
        hs, hsTHi, hsTLo, TS, HH);

    // G1: keys = hs @ Wa, M=8192 N=1024 K=1024, store split
    gemm_split<1, false><<<dim3(HH / 128, (BB * TS) / 128, 1), 256, 0, stream>>>(
        hs, nullptr, WaTHi, WaTLo, nullptr, keysHi, keysLo, nullptr,
        BB * TS, HH, HH, 0, 0, 0);

    // G2: score[b] = ht[b] @ keys[b]^T, M=512 N=512 K=1024, x16 batches
    gemm_split<0, false><<<dim3(TS / 128, TT / 128, BB), 256, 0, stream>>>(
        ht, nullptr, keysHi, keysLo, score, nullptr, nullptr, nullptr,
        TT, TS, HH, (long)TT * HH, (long)TS * HH, (long)TT * TS);

    softmax_mask_kernel<<<BB * TT, 64, 0, stream>>>(score, lens);

    // G3: c[b] = a[b] @ hs[b], M=512 N=1024 K=512, x16 batches
    gemm_split<0, false><<<dim3(HH / 128, TT / 128, BB), 256, 0, stream>>>(
        score, nullptr, hsTHi, hsTLo, cbuf, nullptr, nullptr, nullptr,
        TT, HH, TS, (long)TT * TS, (long)HH * TS, (long)TT * HH);

    // G4: out = tanh(concat(c, ht) @ Wc + b), M=8192 N=1024 K=2048
    gemm_split<2, true><<<dim3(OO / 128, (BB * TT) / 128, 1), 256, 0, stream>>>(
        cbuf, ht, WcTHi, WcTLo, out, nullptr, nullptr, bias,
        BB * TT, OO, 2 * HH, 0, 0, 0);
}

// Round 2
// 286.392 us; speedup vs baseline: 1.1278x; 1.1278x over previous
//
#include <hip/hip_runtime.h>
#include <math.h>

typedef unsigned short u16;
typedef unsigned int u32;

using f32x4 = __attribute__((ext_vector_type(4))) float;
using s16x8 = __attribute__((ext_vector_type(8))) short;
using u32x4 = __attribute__((ext_vector_type(4))) u32;

#define DEVI static __device__ __forceinline__

// ---- problem constants ----
#define BB 16
#define TT 512
#define TS 512
#define HH 1024
#define OO 1024

// split fp32 -> bf16 hi (truncated) + bf16 lo (truncated residual).
// x = hi + lo + eps, |eps| <= 2^-16 |x|.
DEVI void split1(float x, u32& hb, u32& lb) {
    u32 xb = __float_as_uint(x);
    float hf = __uint_as_float(xb & 0xffff0000u);
    hb = xb >> 16;
    lb = __float_as_uint(x - hf) >> 16;
}

DEVI float unsplit(u16 h, u16 l) {
    return __uint_as_float((u32)h << 16) + __uint_as_float((u32)l << 16);
}

// async global->LDS, 16B per lane. LDS dest must be wave-uniform base (+lane*16).
DEVI void gl16(const void* g, void* l) {
    __builtin_amdgcn_global_load_lds(
        (__attribute__((address_space(1))) const void*)g,
        (__attribute__((address_space(3))) void*)l, 16, 0, 0);
}

// lens[b] = count of non-zero source tokens
__global__ void lens_kernel(const int* __restrict__ src, int* __restrict__ lens) {
    int b = blockIdx.x;
    int v = (src[b * TS + (int)threadIdx.x] != 0) ? 1 : 0;
    unsigned long long m = __ballot(v);
    __shared__ int part[8];
    if ((threadIdx.x & 63) == 0) part[threadIdx.x >> 6] = __popcll(m);
    __syncthreads();
    if (threadIdx.x == 0) {
        int s = 0;
#pragma unroll
        for (int i = 0; i < 8; ++i) s += part[i];
        lens[b] = s;
    }
}

// transpose fp32 src[R][C] -> split bf16 hi/lo out[C][R]; grid.z = batch
__global__ void transpose_split_kernel(const float* __restrict__ src,
                                       u16* __restrict__ dhi, u16* __restrict__ dlo,
                                       int R, int C) {
    __shared__ float tile[32][33];
    long boff = (long)blockIdx.z * R * C;
    src += boff; dhi += boff; dlo += boff;
    int c0 = blockIdx.x * 32, r0 = blockIdx.y * 32;
    int tx = threadIdx.x, ty = threadIdx.y;
#pragma unroll
    for (int i = 0; i < 32; i += 8)
        tile[ty + i][tx] = src[(long)(r0 + ty + i) * C + (c0 + tx)];
    __syncthreads();
#pragma unroll
    for (int i = 0; i < 32; i += 8) {
        u32 hb, lb;
        split1(tile[tx][ty + i], hb, lb);
        long o = (long)(c0 + ty + i) * R + (r0 + tx);
        dhi[o] = (u16)hb;
        dlo[o] = (u16)lb;
    }
}

// in-place masked softmax on split score [B*TT][TS], one wave per row.
// Ref semantics: rowmax over FULL row, exp, prefix mask, normalize.
__global__ void softmax_mask_kernel(u16* __restrict__ hi, u16* __restrict__ lo,
                                    const int* __restrict__ lens) {
    long row = blockIdx.x;
    int len = lens[blockIdx.x >> 9];  // TT = 512
    u16* ph = hi + row * TS;
    u16* pl = lo + row * TS;
    int lane = threadIdx.x;
    s16x8 vh = *(const s16x8*)(ph + 8 * lane);
    s16x8 vl = *(const s16x8*)(pl + 8 * lane);
    float f[8];
#pragma unroll
    for (int i = 0; i < 8; ++i) f[i] = unsplit((u16)vh[i], (u16)vl[i]);
    float m = f[0];
#pragma unroll
    for (int i = 1; i < 8; ++i) m = fmaxf(m, f[i]);
#pragma unroll
    for (int o = 32; o > 0; o >>= 1) m = fmaxf(m, __shfl_xor(m, o));
    float e[8];
    float sum = 0.f;
#pragma unroll
    for (int i = 0; i < 8; ++i) {
        e[i] = (8 * lane + i < len) ? expf(f[i] - m) : 0.f;
        sum += e[i];
    }
#pragma unroll
    for (int o = 32; o > 0; o >>= 1) sum += __shfl_xor(sum, o);
    float inv = 1.0f / sum;
#pragma unroll
    for (int i = 0; i < 8; ++i) {
        u32 hb, lb;
        split1(e[i] * inv, hb, lb);
        vh[i] = (short)hb;
        vl[i] = (short)lb;
    }
    *(s16x8*)(ph + 8 * lane) = vh;
    *(s16x8*)(pl + 8 * lane) = vl;
}

// C[m][n] = sum_k A[m][k]*Bt[n][k], double-bf16 (3-term MFMA).
// LDS layout per 128x32 operand tile: byte = row*64 + 16*(slot ^ ((row>>1)&3)),
// slot = k/8. Swizzle applied on the GLOBAL source address for global_load_lds
// (LDS dest stays linear, rule #21) and on ds_write/ds_read addresses.
// ASRC: 0 = pre-split bf16 A via global_load_lds
//       1 = fp32 A, reg-staged + split on the fly
//       2 = concat: k<HH pre-split (Ahi/Alo, lda=HH), k>=HH fp32 Af (lda=HH)
// EPI:  1 = split bf16 hi/lo store, 2 = tanh(x + bias[col]) fp32 store
template <int ASRC, int EPI>
__global__ __launch_bounds__(256, 2)
void gemm_ps(const u16* __restrict__ Ahi, const u16* __restrict__ Alo,
             const float* __restrict__ Af,
             const u16* __restrict__ Bhi, const u16* __restrict__ Blo,
             float* __restrict__ C, u16* __restrict__ Chi, u16* __restrict__ Clo,
             const float* __restrict__ bias,
             int M, int N, int K,
             long sA, long sB, long sC) {
    int bz = blockIdx.z;
    if (ASRC == 0) {
        Ahi += (long)bz * sA;
        Alo += (long)bz * sA;
    } else {
        Af += (long)bz * sA;
    }
    Bhi += (long)bz * sB;
    Blo += (long)bz * sB;

    int n0 = blockIdx.x * 128;
    int m0 = blockIdx.y * 128;

    // [buf][arr*4096 + row*32 + slot*8] u16; arr: 0=Ah 1=Al 2=Bh 3=Bl; 64 KB total
    __shared__ u16 lds[2][4 * 4096];

    int tid = threadIdx.x;
    int lane = tid & 63;
    int wave = tid >> 6;
    int wm = (wave >> 1) * 64;
    int wn = (wave & 1) * 64;
    int fr = lane & 15;
    int kq = lane >> 4;

    const int lda = (ASRC == 2) ? HH : K;

    f32x4 acc[4][4];
#pragma unroll
    for (int i = 0; i < 4; ++i)
#pragma unroll
        for (int j = 0; j < 4; ++j) acc[i][j] = (f32x4){0.f, 0.f, 0.f, 0.f};

    // stage one pre-split operand tile via global_load_lds (source pre-swizzled)
    auto stage_gl = [&](int bufi, int arr, const u16* g, int r0, int ldg, int k0) {
#pragma unroll
        for (int h = 0; h < 2; ++h) {
            int vt = tid + h * 256;               // 0..511 -> LDS byte vt*16
            int row = vt >> 2;                    // 0..127
            int ls = (vt & 3) ^ ((row >> 1) & 3); // logical k-slot at this phys slot
            const u16* gp = g + (long)(r0 + row) * ldg + (k0 + 8 * ls);
            u16* lp = &lds[bufi][arr * 4096 + (vt >> 6) * 512];  // wave-uniform
            gl16(gp, lp);
        }
    };

    // stage fp32 A tile: reg load, split, swizzled ds_write
    auto stage_a_f32 = [&](int bufi, const float* g, int ldg, int kk) {
        int r = tid >> 1;
        int hf = (tid & 1) * 16;
        const float* p = g + (long)(m0 + r) * ldg + kk + hf;
        float4 a0 = *(const float4*)(p + 0);
        float4 a1 = *(const float4*)(p + 4);
        float4 a2 = *(const float4*)(p + 8);
        float4 a3 = *(const float4*)(p + 12);
        float fv[16] = {a0.x, a0.y, a0.z, a0.w, a1.x, a1.y, a1.z, a1.w,
                        a2.x, a2.y, a2.z, a2.w, a3.x, a3.y, a3.z, a3.w};
        u32 hb[16], lb[16];
#pragma unroll
        for (int i = 0; i < 16; ++i) split1(fv[i], hb[i], lb[i]);
        u32x4 h0 = {hb[0] | (hb[1] << 16), hb[2] | (hb[3] << 16),
                    hb[4] | (hb[5] << 16), hb[6] | (hb[7] << 16)};
        u32x4 h1 = {hb[8] | (hb[9] << 16), hb[10] | (hb[11] << 16),
                    hb[12] | (hb[13] << 16), hb[14] | (hb[15] << 16)};
        u32x4 l0 = {lb[0] | (lb[1] << 16), lb[2] | (lb[3] << 16),
                    lb[4] | (lb[5] << 16), lb[6] | (lb[7] << 16)};
        u32x4 l1 = {lb[8] | (lb[9] << 16), lb[10] | (lb[11] << 16),
                    lb[12] | (lb[13] << 16), lb[14] | (lb[15] << 16)};
        int sw = (r >> 1) & 3;
        int ls0 = hf >> 3;  // 0 or 2
        u16* ah = &lds[bufi][0 * 4096 + r * 32];
        u16* al = &lds[bufi][1 * 4096 + r * 32];
        *(u32x4*)(ah + (((ls0 + 0) ^ sw) << 3)) = h0;
        *(u32x4*)(ah + (((ls0 + 1) ^ sw) << 3)) = h1;
        *(u32x4*)(al + (((ls0 + 0) ^ sw) << 3)) = l0;
        *(u32x4*)(al + (((ls0 + 1) ^ sw) << 3)) = l1;
    };

    auto stage = [&](int bufi, int t) {
        int k0 = t * 32;
        stage_gl(bufi, 2, Bhi, n0, K, k0);
        stage_gl(bufi, 3, Blo, n0, K, k0);
        if (ASRC == 0) {
            stage_gl(bufi, 0, Ahi, m0, lda, k0);
            stage_gl(bufi, 1, Alo, m0, lda, k0);
        } else if (ASRC == 1) {
            stage_a_f32(bufi, Af, lda, k0);
        } else {
            if (k0 < HH) {
                stage_gl(bufi, 0, Ahi, m0, lda, k0);
                stage_gl(bufi, 1, Alo, m0, lda, k0);
            } else {
                stage_a_f32(bufi, Af, lda, k0 - HH);
            }
        }
    };

    const int NT = K / 32;
    stage(0, 0);
    __syncthreads();
    int cur = 0;
    for (int t = 0; t < NT; ++t) {
        if (t + 1 < NT) stage(cur ^ 1, t + 1);  // prefetch overlaps compute below

        const u16* L = lds[cur];
        s16x8 afh[4], afl[4], bfh[4], bfl[4];
#pragma unroll
        for (int i = 0; i < 4; ++i) {
            int ra = wm + i * 16 + fr;
            int rb = wn + i * 16 + fr;
            int oa = ra * 32 + ((kq ^ ((ra >> 1) & 3)) << 3);
            int ob = rb * 32 + ((kq ^ ((rb >> 1) & 3)) << 3);
            afh[i] = *(const s16x8*)(L + 0 * 4096 + oa);
            afl[i] = *(const s16x8*)(L + 1 * 4096 + oa);
            bfh[i] = *(const s16x8*)(L + 2 * 4096 + ob);
            bfl[i] = *(const s16x8*)(L + 3 * 4096 + ob);
        }
#pragma unroll
        for (int i = 0; i < 4; ++i)
#pragma unroll
            for (int j = 0; j < 4; ++j) {
                acc[i][j] = __builtin_amdgcn_mfma_f32_16x16x32_bf16(afh[i], bfh[j], acc[i][j], 0, 0, 0);
                acc[i][j] = __builtin_amdgcn_mfma_f32_16x16x32_bf16(afl[i], bfh[j], acc[i][j], 0, 0, 0);
                acc[i][j] = __builtin_amdgcn_mfma_f32_16x16x32_bf16(afh[i], bfl[j], acc[i][j], 0, 0, 0);
            }
        __syncthreads();  // drains prefetch vmcnt + ds_writes, releases buffers
        cur ^= 1;
    }

    // epilogue: C/D layout col = lane&15, row = (lane>>4)*4 + reg (verified r1)
    int fq = (lane >> 4) * 4;
#pragma unroll
    for (int i = 0; i < 4; ++i)
#pragma unroll
        for (int j = 0; j < 4; ++j)
#pragma unroll
            for (int g = 0; g < 4; ++g) {
                int row = m0 + wm + i * 16 + fq + g;
                int col = n0 + wn + j * 16 + fr;
                long idx = (long)bz * sC + (long)row * N + col;
                float v = acc[i][j][g];
                if constexpr (EPI == 1) {
                    u32 h2, l2;
                    split1(v, h2, l2);
                    Chi[idx] = (u16)h2;
                    Clo[idx] = (u16)l2;
                } else {
                    C[idx] = tanhf(v + bias[col]);
                }
            }
}

extern "C" void kernel_launch(void* const* d_in, const int* in_sizes, int n_in,
                              void* d_out, int out_size, void* d_ws, size_t ws_size,
                              hipStream_t stream) {
    const float* ht = (const float*)d_in[0];
    const float* hs = (const float*)d_in[1];
    const int* source = (const int*)d_in[2];
    const float* Wa = (const float*)d_in[3];
    const float* Wc = (const float*)d_in[4];
    const float* bias = (const float*)d_in[5];
    float* out = (float*)d_out;

    char* w = (char*)d_ws;
    size_t off = 0;
    auto alloc = [&](size_t bytes) -> void* {
        void* p = w + off;
        off += (bytes + 255) & ~(size_t)255;
        return p;
    };
    int* lens = (int*)alloc(256);
    u16* keysHi = (u16*)alloc((size_t)BB * TS * HH * 2);   // 16.78 MB
    u16* keysLo = (u16*)alloc((size_t)BB * TS * HH * 2);
    u16* scoreHi = (u16*)alloc((size_t)BB * TT * TS * 2);  // 8.39 MB
    u16* scoreLo = (u16*)alloc((size_t)BB * TT * TS * 2);
    u16* hsTHi = (u16*)alloc((size_t)BB * HH * TS * 2);    // 16.78 MB
    u16* hsTLo = (u16*)alloc((size_t)BB * HH * TS * 2);
    u16* WaTHi = (u16*)alloc((size_t)HH * HH * 2);         // 2.10 MB
    u16* WaTLo = (u16*)alloc((size_t)HH * HH * 2);
    // total ~88.1 MB (< 92.35 MB proven available in round 1)
    // overlays: c[8192][1024] split reuses keys (dead after G2);
    //           WcT[1024][2048] split reuses score (dead after G3; transposed late)
    u16* cHi = keysHi;
    u16* cLo = keysLo;
    u16* WcTHi = scoreHi;
    u16* WcTLo = scoreLo;

    lens_kernel<<<BB, TS, 0, stream>>>(source, lens);
    transpose_split_kernel<<<dim3(HH / 32, HH / 32, 1), dim3(32, 8), 0, stream>>>(
        Wa, WaTHi, WaTLo, HH, HH);
    transpose_split_kernel<<<dim3(HH / 32, TS / 32, BB), dim3(32, 8), 0, stream>>>(
        hs, hsTHi, hsTLo, TS, HH);

    // G1: keys = hs @ Wa  (A = hs fp32, B = WaT split) -> split store
    gemm_ps<1, 1><<<dim3(HH / 128, (BB * TS) / 128, 1), 256, 0, stream>>>(
        nullptr, nullptr, hs, WaTHi, WaTLo,
        nullptr, keysHi, keysLo, nullptr,
        BB * TS, HH, HH, 0, 0, 0);

    // G2: score[b] = ht[b] @ keys[b]^T  (A = ht fp32, B = keys split) -> split store
    gemm_ps<1, 1><<<dim3(TS / 128, TT / 128, BB), 256, 0, stream>>>(
        nullptr, nullptr, ht, keysHi, keysLo,
        nullptr, scoreHi, scoreLo, nullptr,
        TT, TS, HH, (long)TT * HH, (long)TS * HH, (long)TT * TS);

    softmax_mask_kernel<<<BB * TT, 64, 0, stream>>>(scoreHi, scoreLo, lens);

    // G3: c[b] = a[b] @ hs[b]  (A = prob split, B = hsT split) -> split store into c
    gemm_ps<0, 1><<<dim3(HH / 128, TT / 128, BB), 256, 0, stream>>>(
        scoreHi, scoreLo, nullptr, hsTHi, hsTLo,
        nullptr, cHi, cLo, nullptr,
        TT, HH, TS, (long)TT * TS, (long)HH * TS, (long)TT * HH);

    // WcT transpose scheduled late so it can overlay the (now dead) score buffers
    transpose_split_kernel<<<dim3(OO / 32, 2 * HH / 32, 1), dim3(32, 8), 0, stream>>>(
        Wc, WcTHi, WcTLo, 2 * HH, OO);

    // G4: out = tanh(concat(c, ht) @ Wc + b)  (A = c split | ht fp32, B = WcT split)
    gemm_ps<2, 2><<<dim3(OO / 128, (BB * TT) / 128, 1), 256, 0, stream>>>(
        cHi, cLo, ht, WcTHi, WcTLo,
        out, nullptr, nullptr, bias,
        BB * TT, OO, 2 * HH, 0, 0, 0);
}

// Round 3
// 253.949 us; speedup vs baseline: 1.2719x; 1.1278x over previous
//
#include <hip/hip_runtime.h>
#include <math.h>

typedef unsigned short u16;
typedef unsigned int u32;

using f32x4 = __attribute__((ext_vector_type(4))) float;
using s16x8 = __attribute__((ext_vector_type(8))) short;
using u32x4 = __attribute__((ext_vector_type(4))) u32;

#define DEVI static __device__ __forceinline__

// ---- problem constants ----
#define BB 16
#define TT 512
#define TS 512
#define HH 1024
#define OO 1024

// split fp32 -> bf16 hi (truncated) + bf16 lo (truncated residual).
// x = hi + lo + eps, |eps| <= 2^-16 |x|.
DEVI void split1(float x, u32& hb, u32& lb) {
    u32 xb = __float_as_uint(x);
    float hf = __uint_as_float(xb & 0xffff0000u);
    hb = xb >> 16;
    lb = __float_as_uint(x - hf) >> 16;
}

DEVI float unsplit(u16 h, u16 l) {
    return __uint_as_float((u32)h << 16) + __uint_as_float((u32)l << 16);
}

// async global->LDS, 16B per lane. LDS dest must be wave-uniform base (+lane*16).
DEVI void gl16(const void* g, void* l) {
    __builtin_amdgcn_global_load_lds(
        (__attribute__((address_space(1))) const void*)g,
        (__attribute__((address_space(3))) void*)l, 16, 0, 0);
}

// lens[b] = count of non-zero source tokens
__global__ void lens_kernel(const int* __restrict__ src, int* __restrict__ lens) {
    int b = blockIdx.x;
    int v = (src[b * TS + (int)threadIdx.x] != 0) ? 1 : 0;
    unsigned long long m = __ballot(v);
    __shared__ int part[8];
    if ((threadIdx.x & 63) == 0) part[threadIdx.x >> 6] = __popcll(m);
    __syncthreads();
    if (threadIdx.x == 0) {
        int s = 0;
#pragma unroll
        for (int i = 0; i < 8; ++i) s += part[i];
        lens[b] = s;
    }
}

// transpose fp32 src[R][C] -> split bf16 out[C][R]; lo output optional.
__global__ void transpose_split_kernel(const float* __restrict__ src,
                                       u16* __restrict__ dhi, u16* __restrict__ dlo,
                                       int R, int C) {
    __shared__ float tile[32][33];
    long boff = (long)blockIdx.z * R * C;
    src += boff;
    dhi += boff;
    if (dlo) dlo += boff;
    int c0 = blockIdx.x * 32, r0 = blockIdx.y * 32;
    int tx = threadIdx.x, ty = threadIdx.y;
#pragma unroll
    for (int i = 0; i < 32; i += 8)
        tile[ty + i][tx] = src[(long)(r0 + ty + i) * C + (c0 + tx)];
    __syncthreads();
#pragma unroll
    for (int i = 0; i < 32; i += 8) {
        u32 hb, lb;
        split1(tile[tx][ty + i], hb, lb);
        long o = (long)(c0 + ty + i) * R + (r0 + tx);
        dhi[o] = (u16)hb;
        if (dlo) dlo[o] = (u16)lb;
    }
}

// in-place masked softmax on split score [B*TT][TS], one wave per row.
// Ref semantics: rowmax over FULL row, exp, prefix mask, normalize.
__global__ void softmax_mask_kernel(u16* __restrict__ hi, u16* __restrict__ lo,
                                    const int* __restrict__ lens) {
    long row = blockIdx.x;
    int len = lens[blockIdx.x >> 9];  // TT = 512
    u16* ph = hi + row * TS;
    u16* pl = lo + row * TS;
    int lane = threadIdx.x;
    s16x8 vh = *(const s16x8*)(ph + 8 * lane);
    s16x8 vl = *(const s16x8*)(pl + 8 * lane);
    float f[8];
#pragma unroll
    for (int i = 0; i < 8; ++i) f[i] = unsplit((u16)vh[i], (u16)vl[i]);
    float m = f[0];
#pragma unroll
    for (int i = 1; i < 8; ++i) m = fmaxf(m, f[i]);
#pragma unroll
    for (int o = 32; o > 0; o >>= 1) m = fmaxf(m, __shfl_xor(m, o));
    float e[8];
    float sum = 0.f;
#pragma unroll
    for (int i = 0; i < 8; ++i) {
        e[i] = (8 * lane + i < len) ? expf(f[i] - m) : 0.f;
        sum += e[i];
    }
#pragma unroll
    for (int o = 32; o > 0; o >>= 1) sum += __shfl_xor(sum, o);
    float inv = 1.0f / sum;
#pragma unroll
    for (int i = 0; i < 8; ++i) {
        u32 hb, lb;
        split1(e[i] * inv, hb, lb);
        vh[i] = (short)hb;
        vl[i] = (short)lb;
    }
    *(s16x8*)(ph + 8 * lane) = vh;
    *(s16x8*)(pl + 8 * lane) = vl;
}

// C[m][n] = sum_k A[m][k]*Bt[n][k], double-bf16 split arithmetic.
// TERMS=3: Ahi*Bhi + Alo*Bhi + Ahi*Blo (full first-order, score path).
// TERMS=2: Ahi*Bhi + Alo*Bhi (B-lo dropped; B never needs a lo array).
// LDS layout per 128x32 operand tile: off_u16 = row*32 + 8*(slot ^ ((row>>1)&3)).
// Swizzle applied on the GLOBAL source address for global_load_lds (LDS dest
// stays linear, rule #21) and on ds_write/ds_read addresses.
// ASRC: 0 = pre-split bf16 A via global_load_lds
//       1 = fp32 A, reg-staged + split on the fly
//       2 = concat: k<HH pre-split (Ahi/Alo, lda=HH), k>=HH fp32 Af (lda=HH)
// EPI:  1 = split bf16 hi/lo store, 2 = fast-tanh(x + bias[col]) fp32 store
template <int ASRC, int EPI, int TERMS>
__global__ __launch_bounds__(256, 2)
void gemm_ps(const u16* __restrict__ Ahi, const u16* __restrict__ Alo,
             const float* __restrict__ Af,
             const u16* __restrict__ Bhi, const u16* __restrict__ Blo,
             float* __restrict__ C, u16* __restrict__ Chi, u16* __restrict__ Clo,
             const float* __restrict__ bias,
             int M, int N, int K,
             long sA, long sB, long sC) {
    int bz = blockIdx.z;
    if (ASRC == 0) {
        Ahi += (long)bz * sA;
        Alo += (long)bz * sA;
    } else {
        Af += (long)bz * sA;
    }
    Bhi += (long)bz * sB;
    if (TERMS == 3) Blo += (long)bz * sB;

    int n0 = blockIdx.x * 128;
    int m0 = blockIdx.y * 128;

    // arr: 0=Ah 1=Al 2=Bh [3=Bl]; 8KB per arr per buf
    constexpr int NARR = (TERMS == 3) ? 4 : 3;
    __shared__ u16 lds[2][NARR * 4096];

    int tid = threadIdx.x;
    int lane = tid & 63;
    int wave = tid >> 6;
    int wm = (wave >> 1) * 64;
    int wn = (wave & 1) * 64;
    int fr = lane & 15;
    int kq = lane >> 4;

    const int lda = (ASRC == 2) ? HH : K;

    f32x4 acc[4][4];
#pragma unroll
    for (int i = 0; i < 4; ++i)
#pragma unroll
        for (int j = 0; j < 4; ++j) acc[i][j] = (f32x4){0.f, 0.f, 0.f, 0.f};

    // stage one pre-split operand tile via global_load_lds (source pre-swizzled)
    auto stage_gl = [&](int bufi, int arr, const u16* g, int r0, int ldg, int k0) {
#pragma unroll
        for (int h = 0; h < 2; ++h) {
            int vt = tid + h * 256;               // 0..511 -> LDS byte vt*16
            int row = vt >> 2;                    // 0..127
            int ls = (vt & 3) ^ ((row >> 1) & 3); // logical k-slot at this phys slot
            const u16* gp = g + (long)(r0 + row) * ldg + (k0 + 8 * ls);
            u16* lp = &lds[bufi][arr * 4096 + (vt >> 6) * 512];  // wave-uniform
            gl16(gp, lp);
        }
    };

    // stage fp32 A tile: reg load, split, swizzled ds_write
    auto stage_a_f32 = [&](int bufi, const float* g, int ldg, int kk) {
        int r = tid >> 1;
        int hf = (tid & 1) * 16;
        const float* p = g + (long)(m0 + r) * ldg + kk + hf;
        float4 a0 = *(const float4*)(p + 0);
        float4 a1 = *(const float4*)(p + 4);
        float4 a2 = *(const float4*)(p + 8);
        float4 a3 = *(const float4*)(p + 12);
        float fv[16] = {a0.x, a0.y, a0.z, a0.w, a1.x, a1.y, a1.z, a1.w,
                        a2.x, a2.y, a2.z, a2.w, a3.x, a3.y, a3.z, a3.w};
        u32 hb[16], lb[16];
#pragma unroll
        for (int i = 0; i < 16; ++i) split1(fv[i], hb[i], lb[i]);
        u32x4 h0 = {hb[0] | (hb[1] << 16), hb[2] | (hb[3] << 16),
                    hb[4] | (hb[5] << 16), hb[6] | (hb[7] << 16)};
        u32x4 h1 = {hb[8] | (hb[9] << 16), hb[10] | (hb[11] << 16),
                    hb[12] | (hb[13] << 16), hb[14] | (hb[15] << 16)};
        u32x4 l0 = {lb[0] | (lb[1] << 16), lb[2] | (lb[3] << 16),
                    lb[4] | (lb[5] << 16), lb[6] | (lb[7] << 16)};
        u32x4 l1 = {lb[8] | (lb[9] << 16), lb[10] | (lb[11] << 16),
                    lb[12] | (lb[13] << 16), lb[14] | (lb[15] << 16)};
        int sw = (r >> 1) & 3;
        int ls0 = hf >> 3;  // 0 or 2
        u16* ah = &lds[bufi][0 * 4096 + r * 32];
        u16* al = &lds[bufi][1 * 4096 + r * 32];
        *(u32x4*)(ah + (((ls0 + 0) ^ sw) << 3)) = h0;
        *(u32x4*)(ah + (((ls0 + 1) ^ sw) << 3)) = h1;
        *(u32x4*)(al + (((ls0 + 0) ^ sw) << 3)) = l0;
        *(u32x4*)(al + (((ls0 + 1) ^ sw) << 3)) = l1;
    };

    auto stage = [&](int bufi, int t) {
        int k0 = t * 32;
        stage_gl(bufi, 2, Bhi, n0, K, k0);
        if (TERMS == 3) stage_gl(bufi, 3, Blo, n0, K, k0);
        if (ASRC == 0) {
            stage_gl(bufi, 0, Ahi, m0, lda, k0);
            stage_gl(bufi, 1, Alo, m0, lda, k0);
        } else if (ASRC == 1) {
            stage_a_f32(bufi, Af, lda, k0);
        } else {
            if (k0 < HH) {
                stage_gl(bufi, 0, Ahi, m0, lda, k0);
                stage_gl(bufi, 1, Alo, m0, lda, k0);
            } else {
                stage_a_f32(bufi, Af, lda, k0 - HH);
            }
        }
    };

    const int NT = K / 32;
    stage(0, 0);
    __syncthreads();
    int cur = 0;
    for (int t = 0; t < NT; ++t) {
        if (t + 1 < NT) stage(cur ^ 1, t + 1);  // prefetch overlaps compute below

        const u16* L = lds[cur];
        s16x8 afh[4], afl[4], bfh[4], bfl[4];
#pragma unroll
        for (int i = 0; i < 4; ++i) {
            int ra = wm + i * 16 + fr;
            int rb = wn + i * 16 + fr;
            int oa = ra * 32 + ((kq ^ ((ra >> 1) & 3)) << 3);
            int ob = rb * 32 + ((kq ^ ((rb >> 1) & 3)) << 3);
            afh[i] = *(const s16x8*)(L + 0 * 4096 + oa);
            afl[i] = *(const s16x8*)(L + 1 * 4096 + oa);
            bfh[i] = *(const s16x8*)(L + 2 * 4096 + ob);
            if (TERMS == 3) bfl[i] = *(const s16x8*)(L + 3 * 4096 + ob);
        }
#pragma unroll
        for (int i = 0; i < 4; ++i)
#pragma unroll
            for (int j = 0; j < 4; ++j) {
                acc[i][j] = __builtin_amdgcn_mfma_f32_16x16x32_bf16(afh[i], bfh[j], acc[i][j], 0, 0, 0);
                acc[i][j] = __builtin_amdgcn_mfma_f32_16x16x32_bf16(afl[i], bfh[j], acc[i][j], 0, 0, 0);
                if (TERMS == 3)
                    acc[i][j] = __builtin_amdgcn_mfma_f32_16x16x32_bf16(afh[i], bfl[j], acc[i][j], 0, 0, 0);
            }
        __syncthreads();  // drains prefetch vmcnt + ds_writes, releases buffers
        cur ^= 1;
    }

    // epilogue: C/D layout col = lane&15, row = (lane>>4)*4 + reg (verified r1)
    int fq = (lane >> 4) * 4;
#pragma unroll
    for (int i = 0; i < 4; ++i)
#pragma unroll
        for (int j = 0; j < 4; ++j)
#pragma unroll
            for (int g = 0; g < 4; ++g) {
                int row = m0 + wm + i * 16 + fq + g;
                int col = n0 + wn + j * 16 + fr;
                long idx = (long)bz * sC + (long)row * N + col;
                float v = acc[i][j][g];
                if constexpr (EPI == 1) {
                    u32 h2, l2;
                    split1(v, h2, l2);
                    Chi[idx] = (u16)h2;
                    Clo[idx] = (u16)l2;
                } else {
                    // tanh(x) = 1 - 2/(e^{2x}+1); hw exp + rcp, err ~1e-6
                    float x = v + bias[col];
                    float t = __expf(2.f * x);
                    C[idx] = 1.f - 2.f * __builtin_amdgcn_rcpf(t + 1.f);
                }
            }
}

extern "C" void kernel_launch(void* const* d_in, const int* in_sizes, int n_in,
                              void* d_out, int out_size, void* d_ws, size_t ws_size,
                              hipStream_t stream) {
    const float* ht = (const float*)d_in[0];
    const float* hs = (const float*)d_in[1];
    const int* source = (const int*)d_in[2];
    const float* Wa = (const float*)d_in[3];
    const float* Wc = (const float*)d_in[4];
    const float* bias = (const float*)d_in[5];
    float* out = (float*)d_out;

    char* w = (char*)d_ws;
    size_t off = 0;
    auto alloc = [&](size_t bytes) -> void* {
        void* p = w + off;
        off += (bytes + 255) & ~(size_t)255;
        return p;
    };
    int* lens = (int*)alloc(256);
    u16* keysHi = (u16*)alloc((size_t)BB * TS * HH * 2);   // 16.78 MB
    u16* keysLo = (u16*)alloc((size_t)BB * TS * HH * 2);
    u16* scoreHi = (u16*)alloc((size_t)BB * TT * TS * 2);  // 8.39 MB
    u16* scoreLo = (u16*)alloc((size_t)BB * TT * TS * 2);
    u16* hsTHi = (u16*)alloc((size_t)BB * HH * TS * 2);    // 16.78 MB (no lo needed)
    u16* WaTHi = (u16*)alloc((size_t)HH * HH * 2);         // 2.10 MB
    u16* WaTLo = (u16*)alloc((size_t)HH * HH * 2);
    // total ~71.3 MB (< 88.1 MB proven available in round 2)
    // overlays: c[8192][1024] split reuses keys (dead after G2);
    //           WcT hi [1024][2048] reuses scoreHi (dead after G3; transposed late)
    u16* cHi = keysHi;
    u16* cLo = keysLo;
    u16* WcTHi = scoreHi;

    lens_kernel<<<BB, TS, 0, stream>>>(source, lens);
    transpose_split_kernel<<<dim3(HH / 32, HH / 32, 1), dim3(32, 8), 0, stream>>>(
        Wa, WaTHi, WaTLo, HH, HH);
    transpose_split_kernel<<<dim3(HH / 32, TS / 32, BB), dim3(32, 8), 0, stream>>>(
        hs, hsTHi, nullptr, TS, HH);

    // G1: keys = hs @ Wa  (A = hs fp32, B = WaT split, 3-term) -> split store
    gemm_ps<1, 1, 3><<<dim3(HH / 128, (BB * TS) / 128, 1), 256, 0, stream>>>(
        nullptr, nullptr, hs, WaTHi, WaTLo,
        nullptr, keysHi, keysLo, nullptr,
        BB * TS, HH, HH, 0, 0, 0);

    // G2: score[b] = ht[b] @ keys[b]^T  (A = ht fp32, B = keys split, 3-term)
    gemm_ps<1, 1, 3><<<dim3(TS / 128, TT / 128, BB), 256, 0, stream>>>(
        nullptr, nullptr, ht, keysHi, keysLo,
        nullptr, scoreHi, scoreLo, nullptr,
        TT, TS, HH, (long)TT * HH, (long)TS * HH, (long)TT * TS);

    softmax_mask_kernel<<<BB * TT, 64, 0, stream>>>(scoreHi, scoreLo, lens);

    // G3: c[b] = a[b] @ hs[b]  (A = prob split, B = hsT hi only, 2-term)
    gemm_ps<0, 1, 2><<<dim3(HH / 128, TT / 128, BB), 256, 0, stream>>>(
        scoreHi, scoreLo, nullptr, hsTHi, nullptr,
        nullptr, cHi, cLo, nullptr,
        TT, HH, TS, (long)TT * TS, (long)HH * TS, (long)TT * HH);

    // WcT transpose scheduled late so it can overlay the (now dead) score buffer
    transpose_split_kernel<<<dim3(OO / 32, 2 * HH / 32, 1), dim3(32, 8), 0, stream>>>(
        Wc, WcTHi, nullptr, 2 * HH, OO);

    // G4: out = tanh(concat(c, ht) @ Wc + b)  (A = c split | ht fp32, B = WcT hi, 2-term)
    gemm_ps<2, 2, 2><<<dim3(OO / 128, (BB * TT) / 128, 1), 256, 0, stream>>>(
        cHi, cLo, ht, WcTHi, nullptr,
        out, nullptr, nullptr, bias,
        BB * TT, OO, 2 * HH, 0, 0, 0);
}

// Round 4
// 216.763 us; speedup vs baseline: 1.4901x; 1.1716x over previous
//
#include <hip/hip_runtime.h>
#include <math.h>

typedef unsigned short u16;
typedef unsigned int u32;

using f32x4 = __attribute__((ext_vector_type(4))) float;
using f16x8 = __attribute__((ext_vector_type(8))) _Float16;
using u32x4 = __attribute__((ext_vector_type(4))) u32;

#define DEVI static __device__ __forceinline__

// ---- problem constants ----
#define BB 16
#define TT 512
#define TS 512
#define HH 1024
#define OO 1024

#define LO_SCALE 2048.0f
#define LO_INV 4.8828125e-4f  // 1/2048

// split fp32 -> fp16 hi (RN) + fp16 lo = RN((x-hi)*2048).
// x = hi + lo/2048 + eps, |eps| <= 2^-22 |x|. Scaling keeps lo out of
// fp16-subnormal range (weights' lo ~1e-5 would flush otherwise).
DEVI void split1h(float x, u16& hb, u16& lb) {
    _Float16 h = (_Float16)x;
    _Float16 l = (_Float16)((x - (float)h) * LO_SCALE);
    hb = __builtin_bit_cast(u16, h);
    lb = __builtin_bit_cast(u16, l);
}

DEVI float h2f(u16 b) { return (float)__builtin_bit_cast(_Float16, b); }

// async global->LDS, 16B per lane. LDS dest must be wave-uniform base (+lane*16).
DEVI void gl16(const void* g, void* l) {
    __builtin_amdgcn_global_load_lds(
        (__attribute__((address_space(1))) const void*)g,
        (__attribute__((address_space(3))) void*)l, 16, 0, 0);
}

// lens[b] = count of non-zero source tokens
__global__ void lens_kernel(const int* __restrict__ src, int* __restrict__ lens) {
    int b = blockIdx.x;
    int v = (src[b * TS + (int)threadIdx.x] != 0) ? 1 : 0;
    unsigned long long m = __ballot(v);
    __shared__ int part[8];
    if ((threadIdx.x & 63) == 0) part[threadIdx.x >> 6] = __popcll(m);
    __syncthreads();
    if (threadIdx.x == 0) {
        int s = 0;
#pragma unroll
        for (int i = 0; i < 8; ++i) s += part[i];
        lens[b] = s;
    }
}

// transpose fp32 src[R][C] -> split fp16 out[C][R]; lo (scaled x2048) optional.
__global__ void transpose_split_kernel(const float* __restrict__ src,
                                       u16* __restrict__ dhi, u16* __restrict__ dlo,
                                       int R, int C) {
    __shared__ float tile[32][33];
    long boff = (long)blockIdx.z * R * C;
    src += boff;
    dhi += boff;
    if (dlo) dlo += boff;
    int c0 = blockIdx.x * 32, r0 = blockIdx.y * 32;
    int tx = threadIdx.x, ty = threadIdx.y;
#pragma unroll
    for (int i = 0; i < 32; i += 8)
        tile[ty + i][tx] = src[(long)(r0 + ty + i) * C + (c0 + tx)];
    __syncthreads();
#pragma unroll
    for (int i = 0; i < 32; i += 8) {
        u16 hb, lb;
        split1h(tile[tx][ty + i], hb, lb);
        long o = (long)(c0 + ty + i) * R + (r0 + tx);
        dhi[o] = hb;
        if (dlo) dlo[o] = lb;
    }
}

// masked softmax on split-fp16 score [B*TT][TS], one wave per row.
// Reads hi + lo*2^-11 (fp32-accurate score); writes PROB as fp16 hi only
// (prob in [0,1], rel 2^-11 suffices downstream). lo buffer left dead.
__global__ void softmax_mask_kernel(u16* __restrict__ hi, u16* __restrict__ lo,
                                    const int* __restrict__ lens) {
    long row = blockIdx.x;
    int len = lens[blockIdx.x >> 9];  // TT = 512
    u16* ph = hi + row * TS;
    u16* pl = lo + row * TS;
    int lane = threadIdx.x;
    f16x8 vh = *(const f16x8*)(ph + 8 * lane);
    f16x8 vl = *(const f16x8*)(pl + 8 * lane);
    float f[8];
#pragma unroll
    for (int i = 0; i < 8; ++i) f[i] = (float)vh[i] + (float)vl[i] * LO_INV;
    float m = f[0];
#pragma unroll
    for (int i = 1; i < 8; ++i) m = fmaxf(m, f[i]);
#pragma unroll
    for (int o = 32; o > 0; o >>= 1) m = fmaxf(m, __shfl_xor(m, o));
    float e[8];
    float sum = 0.f;
#pragma unroll
    for (int i = 0; i < 8; ++i) {
        e[i] = (8 * lane + i < len) ? expf(f[i] - m) : 0.f;
        sum += e[i];
    }
#pragma unroll
    for (int o = 32; o > 0; o >>= 1) sum += __shfl_xor(sum, o);
    float inv = 1.0f / sum;
#pragma unroll
    for (int i = 0; i < 8; ++i) vh[i] = (_Float16)(e[i] * inv);
    *(f16x8*)(ph + 8 * lane) = vh;
}

// C[m][n] = sum_k A[m][k]*Bt[n][k], fp16-split arithmetic, fp32 MFMA acc.
// TERMS=3: acc += Ah*Bh; acc2 += Al'*Bh + Ah*Bl' (lo ops pre-scaled x2048);
//          value = acc + acc2/2048. ~fp32-exact (residual 2^-22).
// TERMS=1: acc = Ah*Bh only (plain fp16 hi).
// LDS layout per 128x32 operand tile: off_u16 = row*32 + 8*(slot ^ ((row>>1)&3)).
// Swizzle applied on the GLOBAL source address for global_load_lds (LDS dest
// stays linear, rule #21) and on ds_write/ds_read addresses.
// ASRC: 0 = pre-split fp16 A via global_load_lds (hi, + lo if TERMS==3)
//       1 = fp32 A, reg-staged + split on the fly
//       2 = concat: k<HH pre-split HI (lda=HH), k>=HH fp32 Af (lda=HH), hi only
// EPI:  1 = split fp16 hi/lo store, 2 = fast-tanh(x+bias) fp32, 3 = fp16 hi only
// SWZ:  XCD-chunked blockIdx swizzle (1-D grid of 512, decode 8 x 64)
template <int ASRC, int EPI, int TERMS, bool SWZ>
__global__ __launch_bounds__(256, 2)
void gemm_h(const u16* __restrict__ Ahi, const u16* __restrict__ Alo,
            const float* __restrict__ Af,
            const u16* __restrict__ Bhi, const u16* __restrict__ Blo,
            float* __restrict__ C, u16* __restrict__ Chi, u16* __restrict__ Clo,
            const float* __restrict__ bias,
            int M, int N, int K,
            long sA, long sB, long sC) {
    int bx, by, bz;
    if (SWZ) {
        // bijective XCD-chunk swizzle: nwg=512, 8 XCDs, chunk=64.
        // same-XCD blocks cover the same 8 A-panels -> A fetched once per XCD.
        int id = blockIdx.x;
        int ns = ((id & 7) << 6) | (id >> 3);
        bx = ns & 7;
        by = ns >> 3;
        bz = 0;
    } else {
        bx = blockIdx.x;
        by = blockIdx.y;
        bz = blockIdx.z;
    }
    if (ASRC == 0) {
        Ahi += (long)bz * sA;
        if (TERMS == 3) Alo += (long)bz * sA;
    } else if (ASRC == 1) {
        Af += (long)bz * sA;
    }
    Bhi += (long)bz * sB;
    if (TERMS == 3) Blo += (long)bz * sB;

    int n0 = bx * 128;
    int m0 = by * 128;

    // arrays: 0=Ah, 1=Bh (TERMS==1) / 0=Ah, 1=Al, 2=Bh, 3=Bl (TERMS==3)
    constexpr int NARR = (TERMS == 3) ? 4 : 2;
    constexpr int AH = 0;
    constexpr int AL = 1;
    constexpr int BH = (TERMS == 3) ? 2 : 1;
    constexpr int BL = 3;
    __shared__ u16 lds[2][NARR * 4096];

    int tid = threadIdx.x;
    int lane = tid & 63;
    int wave = tid >> 6;
    int wm = (wave >> 1) * 64;
    int wn = (wave & 1) * 64;
    int fr = lane & 15;
    int kq = lane >> 4;

    const int lda = (ASRC == 2) ? HH : K;

    f32x4 acc[4][4];
    f32x4 acc2[TERMS == 3 ? 4 : 1][TERMS == 3 ? 4 : 1];
#pragma unroll
    for (int i = 0; i < 4; ++i)
#pragma unroll
        for (int j = 0; j < 4; ++j) acc[i][j] = (f32x4){0.f, 0.f, 0.f, 0.f};
    if (TERMS == 3) {
#pragma unroll
        for (int i = 0; i < 4; ++i)
#pragma unroll
            for (int j = 0; j < 4; ++j) acc2[i][j] = (f32x4){0.f, 0.f, 0.f, 0.f};
    }

    // stage one pre-split operand tile via global_load_lds (source pre-swizzled)
    auto stage_gl = [&](int bufi, int arr, const u16* g, int r0, int ldg, int k0) {
#pragma unroll
        for (int h = 0; h < 2; ++h) {
            int vt = tid + h * 256;               // 0..511 -> LDS byte vt*16
            int row = vt >> 2;                    // 0..127
            int ls = (vt & 3) ^ ((row >> 1) & 3); // logical k-slot at this phys slot
            const u16* gp = g + (long)(r0 + row) * ldg + (k0 + 8 * ls);
            u16* lp = &lds[bufi][arr * 4096 + (vt >> 6) * 512];  // wave-uniform
            gl16(gp, lp);
        }
    };

    // stage fp32 A tile: reg load, split to fp16 (lo scaled), swizzled ds_write.
    // TERMS==1: hi only.
    auto stage_a_f32 = [&](int bufi, const float* g, int ldg, int kk) {
        int r = tid >> 1;
        int hf = (tid & 1) * 16;
        const float* p = g + (long)(m0 + r) * ldg + kk + hf;
        float4 a0 = *(const float4*)(p + 0);
        float4 a1 = *(const float4*)(p + 4);
        float4 a2 = *(const float4*)(p + 8);
        float4 a3 = *(const float4*)(p + 12);
        float fv[16] = {a0.x, a0.y, a0.z, a0.w, a1.x, a1.y, a1.z, a1.w,
                        a2.x, a2.y, a2.z, a2.w, a3.x, a3.y, a3.z, a3.w};
        u16 hb[16], lb[16];
#pragma unroll
        for (int i = 0; i < 16; ++i) split1h(fv[i], hb[i], lb[i]);
        int sw = (r >> 1) & 3;
        int ls0 = hf >> 3;  // 0 or 2
        u32x4 h0 = {(u32)hb[0] | ((u32)hb[1] << 16), (u32)hb[2] | ((u32)hb[3] << 16),
                    (u32)hb[4] | ((u32)hb[5] << 16), (u32)hb[6] | ((u32)hb[7] << 16)};
        u32x4 h1 = {(u32)hb[8] | ((u32)hb[9] << 16), (u32)hb[10] | ((u32)hb[11] << 16),
                    (u32)hb[12] | ((u32)hb[13] << 16), (u32)hb[14] | ((u32)hb[15] << 16)};
        u16* ah = &lds[bufi][AH * 4096 + r * 32];
        *(u32x4*)(ah + (((ls0 + 0) ^ sw) << 3)) = h0;
        *(u32x4*)(ah + (((ls0 + 1) ^ sw) << 3)) = h1;
        if (TERMS == 3) {
            u32x4 l0 = {(u32)lb[0] | ((u32)lb[1] << 16), (u32)lb[2] | ((u32)lb[3] << 16),
                        (u32)lb[4] | ((u32)lb[5] << 16), (u32)lb[6] | ((u32)lb[7] << 16)};
            u32x4 l1 = {(u32)lb[8] | ((u32)lb[9] << 16), (u32)lb[10] | ((u32)lb[11] << 16),
                        (u32)lb[12] | ((u32)lb[13] << 16), (u32)lb[14] | ((u32)lb[15] << 16)};
            u16* al = &lds[bufi][AL * 4096 + r * 32];
            *(u32x4*)(al + (((ls0 + 0) ^ sw) << 3)) = l0;
            *(u32x4*)(al + (((ls0 + 1) ^ sw) << 3)) = l1;
        }
    };

    auto stage = [&](int bufi, int t) {
        int k0 = t * 32;
        stage_gl(bufi, BH, Bhi, n0, K, k0);
        if (TERMS == 3) stage_gl(bufi, BL, Blo, n0, K, k0);
        if (ASRC == 0) {
            stage_gl(bufi, AH, Ahi, m0, lda, k0);
            if (TERMS == 3) stage_gl(bufi, AL, Alo, m0, lda, k0);
        } else if (ASRC == 1) {
            stage_a_f32(bufi, Af, lda, k0);
        } else {
            if (k0 < HH)
                stage_gl(bufi, AH, Ahi, m0, HH, k0);
            else
                stage_a_f32(bufi, Af, HH, k0 - HH);
        }
    };

    const int NT = K / 32;
    stage(0, 0);
    __syncthreads();
    int cur = 0;
    for (int t = 0; t < NT; ++t) {
        if (t + 1 < NT) stage(cur ^ 1, t + 1);  // prefetch overlaps compute below

        const u16* L = lds[cur];
        f16x8 afh[4], afl[4], bfh[4], bfl[4];
#pragma unroll
        for (int i = 0; i < 4; ++i) {
            int ra = wm + i * 16 + fr;
            int rb = wn + i * 16 + fr;
            int oa = ra * 32 + ((kq ^ ((ra >> 1) & 3)) << 3);
            int ob = rb * 32 + ((kq ^ ((rb >> 1) & 3)) << 3);
            afh[i] = *(const f16x8*)(L + AH * 4096 + oa);
            bfh[i] = *(const f16x8*)(L + BH * 4096 + ob);
            if (TERMS == 3) {
                afl[i] = *(const f16x8*)(L + AL * 4096 + oa);
                bfl[i] = *(const f16x8*)(L + BL * 4096 + ob);
            }
        }
#pragma unroll
        for (int i = 0; i < 4; ++i)
#pragma unroll
            for (int j = 0; j < 4; ++j) {
                acc[i][j] = __builtin_amdgcn_mfma_f32_16x16x32_f16(afh[i], bfh[j], acc[i][j], 0, 0, 0);
                if (TERMS == 3) {
                    acc2[i][j] = __builtin_amdgcn_mfma_f32_16x16x32_f16(afl[i], bfh[j], acc2[i][j], 0, 0, 0);
                    acc2[i][j] = __builtin_amdgcn_mfma_f32_16x16x32_f16(afh[i], bfl[j], acc2[i][j], 0, 0, 0);
                }
            }
        __syncthreads();  // drains prefetch vmcnt + ds_writes, releases buffers
        cur ^= 1;
    }

    // epilogue: C/D layout col = lane&15, row = (lane>>4)*4 + reg (verified r1)
    int fq = (lane >> 4) * 4;
#pragma unroll
    for (int i = 0; i < 4; ++i)
#pragma unroll
        for (int j = 0; j < 4; ++j)
#pragma unroll
            for (int g = 0; g < 4; ++g) {
                int row = m0 + wm + i * 16 + fq + g;
                int col = n0 + wn + j * 16 + fr;
                long idx = (long)bz * sC + (long)row * N + col;
                float v = acc[i][j][g];
                if (TERMS == 3) v += acc2[i][j][g] * LO_INV;
                if constexpr (EPI == 1) {
                    u16 h2, l2;
                    split1h(v, h2, l2);
                    Chi[idx] = h2;
                    Clo[idx] = l2;
                } else if constexpr (EPI == 2) {
                    // tanh(x) = 1 - 2/(e^{2x}+1); hw exp + rcp, err ~1e-6
                    float x = v + bias[col];
                    float t2 = __expf(2.f * x);
                    C[idx] = 1.f - 2.f * __builtin_amdgcn_rcpf(t2 + 1.f);
                } else {
                    Chi[idx] = __builtin_bit_cast(u16, (_Float16)v);
                }
            }
}

extern "C" void kernel_launch(void* const* d_in, const int* in_sizes, int n_in,
                              void* d_out, int out_size, void* d_ws, size_t ws_size,
                              hipStream_t stream) {
    const float* ht = (const float*)d_in[0];
    const float* hs = (const float*)d_in[1];
    const int* source = (const int*)d_in[2];
    const float* Wa = (const float*)d_in[3];
    const float* Wc = (const float*)d_in[4];
    const float* bias = (const float*)d_in[5];
    float* out = (float*)d_out;

    char* w = (char*)d_ws;
    size_t off = 0;
    auto alloc = [&](size_t bytes) -> void* {
        void* p = w + off;
        off += (bytes + 255) & ~(size_t)255;
        return p;
    };
    int* lens = (int*)alloc(256);
    u16* keysHi = (u16*)alloc((size_t)BB * TS * HH * 2);   // 16.78 MB
    u16* keysLo = (u16*)alloc((size_t)BB * TS * HH * 2);
    u16* scoreHi = (u16*)alloc((size_t)BB * TT * TS * 2);  // 8.39 MB
    u16* scoreLo = (u16*)alloc((size_t)BB * TT * TS * 2);
    u16* hsTHi = (u16*)alloc((size_t)BB * HH * TS * 2);    // 16.78 MB (hi only)
    u16* WaTHi = (u16*)alloc((size_t)HH * HH * 2);         // 2.10 MB
    u16* WaTLo = (u16*)alloc((size_t)HH * HH * 2);
    // total ~71.3 MB (proven available in rounds 2-3)
    // overlays: cHi [8192][1024] fp16 reuses keysHi (dead after G2);
    //           WcT hi [1024][2048] fp16 (4.2MB) reuses scoreLo (dead after softmax)
    u16* cHi = keysHi;
    u16* WcTHi = scoreLo;

    lens_kernel<<<BB, TS, 0, stream>>>(source, lens);
    transpose_split_kernel<<<dim3(HH / 32, HH / 32, 1), dim3(32, 8), 0, stream>>>(
        Wa, WaTHi, WaTLo, HH, HH);
    transpose_split_kernel<<<dim3(HH / 32, TS / 32, BB), dim3(32, 8), 0, stream>>>(
        hs, hsTHi, nullptr, TS, HH);

    // G1: keys = hs @ Wa  (A = hs fp32 reg-split, B = WaT hi+lo', 3-term, XCD-swz)
    gemm_h<1, 1, 3, true><<<dim3(512), 256, 0, stream>>>(
        nullptr, nullptr, hs, WaTHi, WaTLo,
        nullptr, keysHi, keysLo, nullptr,
        BB * TS, HH, HH, 0, 0, 0);

    // G2: score[b] = ht[b] @ keys[b]^T  (A = ht fp32 reg-split, B = keys hi+lo', 3-term)
    gemm_h<1, 1, 3, false><<<dim3(TS / 128, TT / 128, BB), 256, 0, stream>>>(
        nullptr, nullptr, ht, keysHi, keysLo,
        nullptr, scoreHi, scoreLo, nullptr,
        TT, TS, HH, (long)TT * HH, (long)TS * HH, (long)TT * TS);

    softmax_mask_kernel<<<BB * TT, 64, 0, stream>>>(scoreHi, scoreLo, lens);

    // G3: c[b] = prob[b] @ hs[b]  (A = prob fp16-hi, B = hsT hi, 1-term) -> c hi fp16
    gemm_h<0, 3, 1, false><<<dim3(HH / 128, TT / 128, BB), 256, 0, stream>>>(
        scoreHi, nullptr, nullptr, hsTHi, nullptr,
        nullptr, cHi, nullptr, nullptr,
        TT, HH, TS, (long)TT * TS, (long)HH * TS, (long)TT * HH);

    // WcT hi transpose scheduled late so it can overlay the (dead) scoreLo buffer
    transpose_split_kernel<<<dim3(OO / 32, 2 * HH / 32, 1), dim3(32, 8), 0, stream>>>(
        Wc, WcTHi, nullptr, 2 * HH, OO);

    // G4: out = tanh(concat(c, ht) @ Wc + b)  (A = cHi | ht fp32->hi, B = WcT hi,
    //     1-term, XCD-swz)
    gemm_h<2, 2, 1, true><<<dim3(512), 256, 0, stream>>>(
        cHi, nullptr, ht, WcTHi, nullptr,
        out, nullptr, nullptr, bias,
        BB * TT, OO, 2 * HH, 0, 0, 0);
}

// Round 5
// 196.352 us; speedup vs baseline: 1.6450x; 1.1040x over previous
//
#include <hip/hip_runtime.h>
#include <math.h>

typedef unsigned short u16;
typedef unsigned int u32;

using f32x4 = __attribute__((ext_vector_type(4))) float;
using s16x8 = __attribute__((ext_vector_type(8))) short;
using f16x8 = __attribute__((ext_vector_type(8))) _Float16;
using u32x4 = __attribute__((ext_vector_type(4))) u32;

#define DEVI static __device__ __forceinline__

// ---- problem constants ----
#define BB 16
#define TT 512
#define TS 512
#define HH 1024
#define OO 1024

// bf16 split: x = hi + lo + eps, |eps| <= 2^-16 |x|; hi-sub exact; no
// subnormal hazard anywhere (bf16 exponent range == fp32). Single-acc 3-term.
DEVI void split_bf(float x, u16& hb, u16& lb) {
    u32 xb = __float_as_uint(x);
    float hf = __uint_as_float(xb & 0xffff0000u);
    hb = (u16)(xb >> 16);
    lb = (u16)(__float_as_uint(x - hf) >> 16);
}

DEVI float ub(u16 h) { return __uint_as_float((u32)h << 16); }

// fragment type per precision: 0 = bf16, 1 = fp16
template <int PREC> struct FragT;
template <> struct FragT<0> { using T = s16x8; };
template <> struct FragT<1> { using T = f16x8; };

DEVI f32x4 mfma16(s16x8 a, s16x8 b, f32x4 c) {
    return __builtin_amdgcn_mfma_f32_16x16x32_bf16(a, b, c, 0, 0, 0);
}
DEVI f32x4 mfma16(f16x8 a, f16x8 b, f32x4 c) {
    return __builtin_amdgcn_mfma_f32_16x16x32_f16(a, b, c, 0, 0, 0);
}

// async global->LDS, 16B per lane. LDS dest must be wave-uniform base (+lane*16).
DEVI void gl16(const void* g, void* l) {
    __builtin_amdgcn_global_load_lds(
        (__attribute__((address_space(1))) const void*)g,
        (__attribute__((address_space(3))) void*)l, 16, 0, 0);
}

// lens[b] = count of non-zero source tokens
__global__ void lens_kernel(const int* __restrict__ src, int* __restrict__ lens) {
    int b = blockIdx.x;
    int v = (src[b * TS + (int)threadIdx.x] != 0) ? 1 : 0;
    unsigned long long m = __ballot(v);
    __shared__ int part[8];
    if ((threadIdx.x & 63) == 0) part[threadIdx.x >> 6] = __popcll(m);
    __syncthreads();
    if (threadIdx.x == 0) {
        int s = 0;
#pragma unroll
        for (int i = 0; i < 8; ++i) s += part[i];
        lens[b] = s;
    }
}

// transpose fp32 src[R][C] -> out[C][R]. PREC=0: bf16 split hi+lo.
// PREC=1: fp16 hi only (dlo ignored).
template <int PREC>
__global__ void transpose_split_kernel(const float* __restrict__ src,
                                       u16* __restrict__ dhi, u16* __restrict__ dlo,
                                       int R, int C) {
    __shared__ float tile[32][33];
    long boff = (long)blockIdx.z * R * C;
    src += boff;
    dhi += boff;
    if (PREC == 0) dlo += boff;
    int c0 = blockIdx.x * 32, r0 = blockIdx.y * 32;
    int tx = threadIdx.x, ty = threadIdx.y;
#pragma unroll
    for (int i = 0; i < 32; i += 8)
        tile[ty + i][tx] = src[(long)(r0 + ty + i) * C + (c0 + tx)];
    __syncthreads();
#pragma unroll
    for (int i = 0; i < 32; i += 8) {
        float v = tile[tx][ty + i];
        long o = (long)(c0 + ty + i) * R + (r0 + tx);
        if constexpr (PREC == 0) {
            u16 hb, lb;
            split_bf(v, hb, lb);
            dhi[o] = hb;
            dlo[o] = lb;
        } else {
            dhi[o] = __builtin_bit_cast(u16, (_Float16)v);
        }
    }
}

// masked softmax over split-K score: full score = (h0+l0) + (h1+l1), bf16 parts.
// One wave per row. Ref semantics: rowmax over FULL row, exp, prefix mask,
// normalize. Writes prob as fp16 into h0 (consumed by G3 as fp16-hi A).
__global__ void softmax_mask_kernel(u16* __restrict__ h0, u16* __restrict__ l0,
                                    const u16* __restrict__ h1, const u16* __restrict__ l1,
                                    const int* __restrict__ lens) {
    long row = blockIdx.x;
    int len = lens[blockIdx.x >> 9];  // TT = 512
    int lane = threadIdx.x;
    long o = row * TS + 8 * lane;
    s16x8 vh0 = *(const s16x8*)(h0 + o);
    s16x8 vl0 = *(const s16x8*)(l0 + o);
    s16x8 vh1 = *(const s16x8*)(h1 + o);
    s16x8 vl1 = *(const s16x8*)(l1 + o);
    float f[8];
#pragma unroll
    for (int i = 0; i < 8; ++i)
        f[i] = (ub((u16)vh0[i]) + ub((u16)vl0[i])) + (ub((u16)vh1[i]) + ub((u16)vl1[i]));
    float m = f[0];
#pragma unroll
    for (int i = 1; i < 8; ++i) m = fmaxf(m, f[i]);
#pragma unroll
    for (int os = 32; os > 0; os >>= 1) m = fmaxf(m, __shfl_xor(m, os));
    float e[8];
    float sum = 0.f;
#pragma unroll
    for (int i = 0; i < 8; ++i) {
        e[i] = (8 * lane + i < len) ? expf(f[i] - m) : 0.f;
        sum += e[i];
    }
#pragma unroll
    for (int os = 32; os > 0; os >>= 1) sum += __shfl_xor(sum, os);
    float inv = 1.0f / sum;
    f16x8 p;
#pragma unroll
    for (int i = 0; i < 8; ++i) p[i] = (_Float16)(e[i] * inv);
    *(f16x8*)(h0 + o) = p;
}

// C[m][n] = sum_k A[m][k]*Bt[n][k].
// PREC=0: bf16, TERMS=3 single-acc (AhBh + AlBh + AhBl, residual ~2^-16).
// PREC=1: fp16, TERMS=1 (hi only, rel 2^-12).
// LDS per 128x32 tile: off_u16 = row*32 + 8*(slot ^ ((row>>1)&3)); swizzle
// applied on global src for global_load_lds (LDS dest linear, rule #21).
// ASRC: 0 = pre-split A via global_load_lds; 1 = fp32 A reg-staged+split;
//       2 = concat (k<HH: pre-split hi, lda; k>=HH: fp32 Af, lda)
// EPI:  1 = bf16 split hi/lo store; 2 = fast-tanh(x+bias) fp32; 3 = fp16 hi
// KSPLIT: 2 -> bz = (batch<<1)|kh; k-range kh*K..+K, output += kh*sKh
// SWZ:  XCD-chunked 1-D grid of 512 (decode 8 x 64)
template <int PREC, int ASRC, int EPI, int TERMS, int KSPLIT, bool SWZ>
__global__ __launch_bounds__(256, 2)
void gemm_u(const u16* __restrict__ Ahi, const u16* __restrict__ Alo,
            const float* __restrict__ Af,
            const u16* __restrict__ Bhi, const u16* __restrict__ Blo,
            float* __restrict__ C, u16* __restrict__ Chi, u16* __restrict__ Clo,
            const float* __restrict__ bias,
            int M, int N, int K, int lda, int ldb,
            long sA, long sB, long sC, long sKh) {
    int bx, by, bz;
    if (SWZ) {
        int id = blockIdx.x;  // nwg=512, 8 XCDs, chunk 64; bijective
        int ns = ((id & 7) << 6) | (id >> 3);
        bx = ns & 7;
        by = ns >> 3;
        bz = 0;
    } else {
        bx = blockIdx.x;
        by = blockIdx.y;
        bz = blockIdx.z;
    }
    int kh = 0;
    if (KSPLIT == 2) {
        kh = bz & 1;
        bz >>= 1;
    }
    if (ASRC == 0) {
        Ahi += (long)bz * sA + (long)kh * K;
        if (TERMS == 3) Alo += (long)bz * sA + (long)kh * K;
    } else if (ASRC == 1) {
        Af += (long)bz * sA + (long)kh * K;
    }
    Bhi += (long)bz * sB + (long)kh * K;
    if (TERMS == 3) Blo += (long)bz * sB + (long)kh * K;

    int n0 = bx * 128;
    int m0 = by * 128;

    constexpr int NARR = (TERMS == 3) ? 4 : 2;
    constexpr int AH = 0, AL = 1;
    constexpr int BH = (TERMS == 3) ? 2 : 1;
    constexpr int BL = 3;
    __shared__ u16 lds[2][NARR * 4096];

    int tid = threadIdx.x;
    int lane = tid & 63;
    int wave = tid >> 6;
    int wm = (wave >> 1) * 64;
    int wn = (wave & 1) * 64;
    int fr = lane & 15;
    int kq = lane >> 4;

    f32x4 acc[4][4];
#pragma unroll
    for (int i = 0; i < 4; ++i)
#pragma unroll
        for (int j = 0; j < 4; ++j) acc[i][j] = (f32x4){0.f, 0.f, 0.f, 0.f};

    auto stage_gl = [&](int bufi, int arr, const u16* g, int r0, int ldg, int k0) {
#pragma unroll
        for (int h = 0; h < 2; ++h) {
            int vt = tid + h * 256;               // 0..511 -> LDS byte vt*16
            int row = vt >> 2;                    // 0..127
            int ls = (vt & 3) ^ ((row >> 1) & 3); // logical k-slot at this phys slot
            const u16* gp = g + (long)(r0 + row) * ldg + (k0 + 8 * ls);
            u16* lp = &lds[bufi][arr * 4096 + (vt >> 6) * 512];  // wave-uniform
            gl16(gp, lp);
        }
    };

    // stage fp32 A tile: reg load, split (PREC0: bf16 hi+lo; PREC1: f16 hi),
    // swizzled ds_write
    auto stage_a_f32 = [&](int bufi, const float* g, int ldg, int kk) {
        int r = tid >> 1;
        int hf = (tid & 1) * 16;
        const float* p = g + (long)(m0 + r) * ldg + kk + hf;
        float4 a0 = *(const float4*)(p + 0);
        float4 a1 = *(const float4*)(p + 4);
        float4 a2 = *(const float4*)(p + 8);
        float4 a3 = *(const float4*)(p + 12);
        float fv[16] = {a0.x, a0.y, a0.z, a0.w, a1.x, a1.y, a1.z, a1.w,
                        a2.x, a2.y, a2.z, a2.w, a3.x, a3.y, a3.z, a3.w};
        u16 hb[16], lb[16];
#pragma unroll
        for (int i = 0; i < 16; ++i) {
            if constexpr (PREC == 0)
                split_bf(fv[i], hb[i], lb[i]);
            else
                hb[i] = __builtin_bit_cast(u16, (_Float16)fv[i]);
        }
        int sw = (r >> 1) & 3;
        int ls0 = hf >> 3;  // 0 or 2
        u32x4 h0 = {(u32)hb[0] | ((u32)hb[1] << 16), (u32)hb[2] | ((u32)hb[3] << 16),
                    (u32)hb[4] | ((u32)hb[5] << 16), (u32)hb[6] | ((u32)hb[7] << 16)};
        u32x4 h1 = {(u32)hb[8] | ((u32)hb[9] << 16), (u32)hb[10] | ((u32)hb[11] << 16),
                    (u32)hb[12] | ((u32)hb[13] << 16), (u32)hb[14] | ((u32)hb[15] << 16)};
        u16* ah = &lds[bufi][AH * 4096 + r * 32];
        *(u32x4*)(ah + (((ls0 + 0) ^ sw) << 3)) = h0;
        *(u32x4*)(ah + (((ls0 + 1) ^ sw) << 3)) = h1;
        if constexpr (TERMS == 3) {
            u32x4 l0 = {(u32)lb[0] | ((u32)lb[1] << 16), (u32)lb[2] | ((u32)lb[3] << 16),
                        (u32)lb[4] | ((u32)lb[5] << 16), (u32)lb[6] | ((u32)lb[7] << 16)};
            u32x4 l1 = {(u32)lb[8] | ((u32)lb[9] << 16), (u32)lb[10] | ((u32)lb[11] << 16),
                        (u32)lb[12] | ((u32)lb[13] << 16), (u32)lb[14] | ((u32)lb[15] << 16)};
            u16* al = &lds[bufi][AL * 4096 + r * 32];
            *(u32x4*)(al + (((ls0 + 0) ^ sw) << 3)) = l0;
            *(u32x4*)(al + (((ls0 + 1) ^ sw) << 3)) = l1;
        }
    };

    auto stage = [&](int bufi, int t) {
        int k0 = t * 32;
        stage_gl(bufi, BH, Bhi, n0, ldb, k0);
        if (TERMS == 3) stage_gl(bufi, BL, Blo, n0, ldb, k0);
        if (ASRC == 0) {
            stage_gl(bufi, AH, Ahi, m0, lda, k0);
            if (TERMS == 3) stage_gl(bufi, AL, Alo, m0, lda, k0);
        } else if (ASRC == 1) {
            stage_a_f32(bufi, Af, lda, k0);
        } else {
            if (k0 < HH)
                stage_gl(bufi, AH, Ahi, m0, lda, k0);
            else
                stage_a_f32(bufi, Af, lda, k0 - HH);
        }
    };

    const int NT = K / 32;
    stage(0, 0);
    __syncthreads();
    int cur = 0;
    using FT = typename FragT<PREC>::T;
    for (int t = 0; t < NT; ++t) {
        if (t + 1 < NT) stage(cur ^ 1, t + 1);  // prefetch overlaps compute below

        const u16* L = lds[cur];
        FT afh[4], afl[4], bfh[4], bfl[4];
#pragma unroll
        for (int i = 0; i < 4; ++i) {
            int ra = wm + i * 16 + fr;
            int rb = wn + i * 16 + fr;
            int oa = ra * 32 + ((kq ^ ((ra >> 1) & 3)) << 3);
            int ob = rb * 32 + ((kq ^ ((rb >> 1) & 3)) << 3);
            afh[i] = *(const FT*)(L + AH * 4096 + oa);
            bfh[i] = *(const FT*)(L + BH * 4096 + ob);
            if (TERMS == 3) {
                afl[i] = *(const FT*)(L + AL * 4096 + oa);
                bfl[i] = *(const FT*)(L + BL * 4096 + ob);
            }
        }
#pragma unroll
        for (int i = 0; i < 4; ++i)
#pragma unroll
            for (int j = 0; j < 4; ++j) {
                acc[i][j] = mfma16(afh[i], bfh[j], acc[i][j]);
                if (TERMS == 3) {
                    acc[i][j] = mfma16(afl[i], bfh[j], acc[i][j]);
                    acc[i][j] = mfma16(afh[i], bfl[j], acc[i][j]);
                }
            }
        __syncthreads();  // drains prefetch vmcnt + ds_writes, releases buffers
        cur ^= 1;
    }

    // epilogue: C/D layout col = lane&15, row = (lane>>4)*4 + reg (verified r1)
    long obase = (long)bz * sC + (long)kh * sKh;
    int fq = (lane >> 4) * 4;
#pragma unroll
    for (int i = 0; i < 4; ++i)
#pragma unroll
        for (int j = 0; j < 4; ++j)
#pragma unroll
            for (int g = 0; g < 4; ++g) {
                int row = m0 + wm + i * 16 + fq + g;
                int col = n0 + wn + j * 16 + fr;
                long idx = obase + (long)row * N + col;
                float v = acc[i][j][g];
                if constexpr (EPI == 1) {
                    u16 h2, l2;
                    split_bf(v, h2, l2);
                    Chi[idx] = h2;
                    Clo[idx] = l2;
                } else if constexpr (EPI == 2) {
                    // tanh(x) = 1 - 2/(e^{2x}+1); hw exp + rcp, err ~1e-6
                    float x = v + bias[col];
                    float t2 = __expf(2.f * x);
                    C[idx] = 1.f - 2.f * __builtin_amdgcn_rcpf(t2 + 1.f);
                } else {
                    Chi[idx] = __builtin_bit_cast(u16, (_Float16)v);
                }
            }
}

extern "C" void kernel_launch(void* const* d_in, const int* in_sizes, int n_in,
                              void* d_out, int out_size, void* d_ws, size_t ws_size,
                              hipStream_t stream) {
    const float* ht = (const float*)d_in[0];
    const float* hs = (const float*)d_in[1];
    const int* source = (const int*)d_in[2];
    const float* Wa = (const float*)d_in[3];
    const float* Wc = (const float*)d_in[4];
    const float* bias = (const float*)d_in[5];
    float* out = (float*)d_out;

    char* w = (char*)d_ws;
    size_t off = 0;
    auto alloc = [&](size_t bytes) -> void* {
        void* p = w + off;
        off += (bytes + 255) & ~(size_t)255;
        return p;
    };
    int* lens = (int*)alloc(256);
    u16* keysHi = (u16*)alloc((size_t)BB * TS * HH * 2);    // 16.78 MB (bf16)
    u16* keysLo = (u16*)alloc((size_t)BB * TS * HH * 2);
    // split-K score: H0,H1 contiguous (kh stride = BB*TT*TS elems), then L0,L1
    u16* scoreH0 = (u16*)alloc((size_t)BB * TT * TS * 2);   // 8.39 MB each
    u16* scoreH1 = (u16*)alloc((size_t)BB * TT * TS * 2);
    u16* scoreL0 = (u16*)alloc((size_t)BB * TT * TS * 2);
    u16* scoreL1 = (u16*)alloc((size_t)BB * TT * TS * 2);
    u16* hsTHi = (u16*)alloc((size_t)BB * HH * TS * 2);     // 16.78 MB (f16 hi)
    u16* WaTHi = (u16*)alloc((size_t)HH * HH * 2);          // 2.10 MB (bf16)
    u16* WaTLo = (u16*)alloc((size_t)HH * HH * 2);
    // total ~88.1 MB (96.5 MB proven available in round 1)
    // overlays: cHi f16 [8192][1024] reuses keysHi (dead after G2);
    //           WcTHi f16 [1024][2048] reuses scoreL0 (dead after softmax)
    u16* cHi = keysHi;
    u16* WcTHi = scoreL0;
    u16* prob = scoreH0;  // softmax writes f16 prob in place of scoreH0

    lens_kernel<<<BB, TS, 0, stream>>>(source, lens);
    transpose_split_kernel<0><<<dim3(HH / 32, HH / 32, 1), dim3(32, 8), 0, stream>>>(
        Wa, WaTHi, WaTLo, HH, HH);
    transpose_split_kernel<1><<<dim3(HH / 32, TS / 32, BB), dim3(32, 8), 0, stream>>>(
        hs, hsTHi, nullptr, TS, HH);

    // G1: keys = hs @ Wa  (bf16 3-term, A = hs fp32 reg-split, XCD-swz)
    gemm_u<0, 1, 1, 3, 1, true><<<dim3(512), 256, 0, stream>>>(
        nullptr, nullptr, hs, WaTHi, WaTLo,
        nullptr, keysHi, keysLo, nullptr,
        BB * TS, HH, HH, HH, HH, 0, 0, 0, 0);

    // G2: score[b] = ht[b] @ keys[b]^T  (bf16 3-term, split-K=2 -> 512 blocks)
    gemm_u<0, 1, 1, 3, 2, false><<<dim3(TS / 128, TT / 128, 2 * BB), 256, 0, stream>>>(
        nullptr, nullptr, ht, keysHi, keysLo,
        nullptr, scoreH0, scoreL0, nullptr,
        TT, TS, HH / 2, HH, HH,
        (long)TT * HH, (long)TS * HH, (long)TT * TS, (long)BB * TT * TS);

    softmax_mask_kernel<<<BB * TT, 64, 0, stream>>>(scoreH0, scoreL0, scoreH1, scoreL1, lens);

    // G3: c[b] = prob[b] @ hs[b]  (f16 1-term) -> c f16 hi
    gemm_u<1, 0, 3, 1, 1, false><<<dim3(HH / 128, TT / 128, BB), 256, 0, stream>>>(
        prob, nullptr, nullptr, hsTHi, nullptr,
        nullptr, cHi, nullptr, nullptr,
        TT, HH, TS, TS, TS,
        (long)TT * TS, (long)HH * TS, (long)TT * HH, 0);

    // WcT f16-hi transpose scheduled late to overlay the (dead) scoreL0 buffer
    transpose_split_kernel<1><<<dim3(OO / 32, 2 * HH / 32, 1), dim3(32, 8), 0, stream>>>(
        Wc, WcTHi, nullptr, 2 * HH, OO);

    // G4: out = tanh(concat(c, ht) @ Wc + b)  (f16 1-term, XCD-swz)
    gemm_u<1, 2, 2, 1, 1, true><<<dim3(512), 256, 0, stream>>>(
        cHi, nullptr, ht, WcTHi, nullptr,
        out, nullptr, nullptr, bias,
        BB * TT, OO, 2 * HH, HH, 2 * HH, 0, 0, 0, 0);
}

// Round 6
// 195.863 us; speedup vs baseline: 1.6491x; 1.0025x over previous
//
#include <hip/hip_runtime.h>
#include <math.h>

typedef unsigned short u16;
typedef unsigned int u32;

using f32x4 = __attribute__((ext_vector_type(4))) float;
using s16x8 = __attribute__((ext_vector_type(8))) short;
using f16x8 = __attribute__((ext_vector_type(8))) _Float16;
using u32x4 = __attribute__((ext_vector_type(4))) u32;

#define DEVI static __device__ __forceinline__

// ---- problem constants ----
#define BB 16
#define TT 512
#define TS 512
#define HH 1024
#define OO 1024

// bf16 split: x = hi + lo + eps, |eps| <= 2^-16 |x|; hi-sub exact; no
// subnormal hazard anywhere (bf16 exponent range == fp32). Single-acc 3-term.
DEVI void split_bf(float x, u16& hb, u16& lb) {
    u32 xb = __float_as_uint(x);
    float hf = __uint_as_float(xb & 0xffff0000u);
    hb = (u16)(xb >> 16);
    lb = (u16)(__float_as_uint(x - hf) >> 16);
}

DEVI float ub(u16 h) { return __uint_as_float((u32)h << 16); }

// fragment type per precision: 0 = bf16, 1 = fp16
template <int PREC> struct FragT;
template <> struct FragT<0> { using T = s16x8; };
template <> struct FragT<1> { using T = f16x8; };

DEVI f32x4 mfma16(s16x8 a, s16x8 b, f32x4 c) {
    return __builtin_amdgcn_mfma_f32_16x16x32_bf16(a, b, c, 0, 0, 0);
}
DEVI f32x4 mfma16(f16x8 a, f16x8 b, f32x4 c) {
    return __builtin_amdgcn_mfma_f32_16x16x32_f16(a, b, c, 0, 0, 0);
}

// async global->LDS, 16B per lane. LDS dest must be wave-uniform base (+lane*16).
DEVI void gl16(const void* g, void* l) {
    __builtin_amdgcn_global_load_lds(
        (__attribute__((address_space(1))) const void*)g,
        (__attribute__((address_space(3))) void*)l, 16, 0, 0);
}

// lens[b] = count of non-zero source tokens
__global__ void lens_kernel(const int* __restrict__ src, int* __restrict__ lens) {
    int b = blockIdx.x;
    int v = (src[b * TS + (int)threadIdx.x] != 0) ? 1 : 0;
    unsigned long long m = __ballot(v);
    __shared__ int part[8];
    if ((threadIdx.x & 63) == 0) part[threadIdx.x >> 6] = __popcll(m);
    __syncthreads();
    if (threadIdx.x == 0) {
        int s = 0;
#pragma unroll
        for (int i = 0; i < 8; ++i) s += part[i];
        lens[b] = s;
    }
}

// transpose fp32 src[R][C] -> out[C][R]. PREC=0: bf16 split hi+lo.
// PREC=1: fp16 hi only (dlo ignored).
template <int PREC>
__global__ void transpose_split_kernel(const float* __restrict__ src,
                                       u16* __restrict__ dhi, u16* __restrict__ dlo,
                                       int R, int C) {
    __shared__ float tile[32][33];
    long boff = (long)blockIdx.z * R * C;
    src += boff;
    dhi += boff;
    if (PREC == 0) dlo += boff;
    int c0 = blockIdx.x * 32, r0 = blockIdx.y * 32;
    int tx = threadIdx.x, ty = threadIdx.y;
#pragma unroll
    for (int i = 0; i < 32; i += 8)
        tile[ty + i][tx] = src[(long)(r0 + ty + i) * C + (c0 + tx)];
    __syncthreads();
#pragma unroll
    for (int i = 0; i < 32; i += 8) {
        float v = tile[tx][ty + i];
        long o = (long)(c0 + ty + i) * R + (r0 + tx);
        if constexpr (PREC == 0) {
            u16 hb, lb;
            split_bf(v, hb, lb);
            dhi[o] = hb;
            dlo[o] = lb;
        } else {
            dhi[o] = __builtin_bit_cast(u16, (_Float16)v);
        }
    }
}

// hs prep: one read of hs [TS][HH] per batch produces
//   (a) hsR row-major bf16 hi/lo (G1's A operand, enables pure global_load_lds)
//   (b) hsT [HH][TS] fp16 hi (G3's B operand)
__global__ void hs_prep_kernel(const float* __restrict__ src,
                               u16* __restrict__ rhi, u16* __restrict__ rlo,
                               u16* __restrict__ thi) {
    __shared__ float tile[32][33];
    long boff = (long)blockIdx.z * TS * HH;
    src += boff;
    rhi += boff;
    rlo += boff;
    thi += boff;
    int c0 = blockIdx.x * 32, r0 = blockIdx.y * 32;
    int tx = threadIdx.x, ty = threadIdx.y;
#pragma unroll
    for (int i = 0; i < 32; i += 8) {
        long o = (long)(r0 + ty + i) * HH + (c0 + tx);
        float v = src[o];
        tile[ty + i][tx] = v;
        u16 hb, lb;
        split_bf(v, hb, lb);
        rhi[o] = hb;  // coalesced: tx contiguous
        rlo[o] = lb;
    }
    __syncthreads();
#pragma unroll
    for (int i = 0; i < 32; i += 8) {
        long o = (long)(c0 + ty + i) * TS + (r0 + tx);
        thi[o] = __builtin_bit_cast(u16, (_Float16)tile[tx][ty + i]);
    }
}

// masked softmax over split-K score: full score = (h0+l0) + (h1+l1), bf16 parts.
// One wave per row. Ref semantics: rowmax over FULL row, exp, prefix mask,
// normalize. Writes prob as fp16 into h0 (consumed by G3 as fp16-hi A).
__global__ void softmax_mask_kernel(u16* __restrict__ h0, u16* __restrict__ l0,
                                    const u16* __restrict__ h1, const u16* __restrict__ l1,
                                    const int* __restrict__ lens) {
    long row = blockIdx.x;
    int len = lens[blockIdx.x >> 9];  // TT = 512
    int lane = threadIdx.x;
    long o = row * TS + 8 * lane;
    s16x8 vh0 = *(const s16x8*)(h0 + o);
    s16x8 vl0 = *(const s16x8*)(l0 + o);
    s16x8 vh1 = *(const s16x8*)(h1 + o);
    s16x8 vl1 = *(const s16x8*)(l1 + o);
    float f[8];
#pragma unroll
    for (int i = 0; i < 8; ++i)
        f[i] = (ub((u16)vh0[i]) + ub((u16)vl0[i])) + (ub((u16)vh1[i]) + ub((u16)vl1[i]));
    float m = f[0];
#pragma unroll
    for (int i = 1; i < 8; ++i) m = fmaxf(m, f[i]);
#pragma unroll
    for (int os = 32; os > 0; os >>= 1) m = fmaxf(m, __shfl_xor(m, os));
    float e[8];
    float sum = 0.f;
#pragma unroll
    for (int i = 0; i < 8; ++i) {
        e[i] = (8 * lane + i < len) ? expf(f[i] - m) : 0.f;
        sum += e[i];
    }
#pragma unroll
    for (int os = 32; os > 0; os >>= 1) sum += __shfl_xor(sum, os);
    float inv = 1.0f / sum;
    f16x8 p;
#pragma unroll
    for (int i = 0; i < 8; ++i) p[i] = (_Float16)(e[i] * inv);
    *(f16x8*)(h0 + o) = p;
}

// C[m][n] = sum_k A[m][k]*Bt[n][k].
// PREC=0: bf16, TERMS=3 single-acc (AhBh + AlBh + AhBl, residual ~2^-16).
// PREC=1: fp16, TERMS=1 (hi only, rel 2^-12).
// LDS per 128x32 tile: off_u16 = row*32 + 8*(slot ^ ((row>>1)&3)); swizzle
// applied on global src for global_load_lds (LDS dest linear, rule #21).
// ASRC: 0 = pre-split A via global_load_lds; 1 = fp32 A reg-staged+split;
//       2 = concat (k<HH: pre-split hi, lda; k>=HH: fp32 Af, lda)
// EPI:  1 = bf16 split hi/lo store; 2 = fast-tanh(x+bias) fp32; 3 = fp16 hi
// KSPLIT: 2 -> bz = (batch<<1)|kh; k-range kh*K..+K, output += kh*sKh
// SWZ:  XCD-chunked 1-D grid of 512 (decode 8 x 64)
template <int PREC, int ASRC, int EPI, int TERMS, int KSPLIT, bool SWZ>
__global__ __launch_bounds__(256, 2)
void gemm_u(const u16* __restrict__ Ahi, const u16* __restrict__ Alo,
            const float* __restrict__ Af,
            const u16* __restrict__ Bhi, const u16* __restrict__ Blo,
            float* __restrict__ C, u16* __restrict__ Chi, u16* __restrict__ Clo,
            const float* __restrict__ bias,
            int M, int N, int K, int lda, int ldb,
            long sA, long sB, long sC, long sKh) {
    int bx, by, bz;
    if (SWZ) {
        int id = blockIdx.x;  // nwg=512, 8 XCDs, chunk 64; bijective
        int ns = ((id & 7) << 6) | (id >> 3);
        bx = ns & 7;
        by = ns >> 3;
        bz = 0;
    } else {
        bx = blockIdx.x;
        by = blockIdx.y;
        bz = blockIdx.z;
    }
    int kh = 0;
    if (KSPLIT == 2) {
        kh = bz & 1;
        bz >>= 1;
    }
    if (ASRC == 0) {
        Ahi += (long)bz * sA + (long)kh * K;
        if (TERMS == 3) Alo += (long)bz * sA + (long)kh * K;
    } else if (ASRC == 1) {
        Af += (long)bz * sA + (long)kh * K;
    }
    Bhi += (long)bz * sB + (long)kh * K;
    if (TERMS == 3) Blo += (long)bz * sB + (long)kh * K;

    int n0 = bx * 128;
    int m0 = by * 128;

    constexpr int NARR = (TERMS == 3) ? 4 : 2;
    constexpr int AH = 0, AL = 1;
    constexpr int BH = (TERMS == 3) ? 2 : 1;
    constexpr int BL = 3;
    __shared__ u16 lds[2][NARR * 4096];

    int tid = threadIdx.x;
    int lane = tid & 63;
    int wave = tid >> 6;
    int wm = (wave >> 1) * 64;
    int wn = (wave & 1) * 64;
    int fr = lane & 15;
    int kq = lane >> 4;

    f32x4 acc[4][4];
#pragma unroll
    for (int i = 0; i < 4; ++i)
#pragma unroll
        for (int j = 0; j < 4; ++j) acc[i][j] = (f32x4){0.f, 0.f, 0.f, 0.f};

    auto stage_gl = [&](int bufi, int arr, const u16* g, int r0, int ldg, int k0) {
#pragma unroll
        for (int h = 0; h < 2; ++h) {
            int vt = tid + h * 256;               // 0..511 -> LDS byte vt*16
            int row = vt >> 2;                    // 0..127
            int ls = (vt & 3) ^ ((row >> 1) & 3); // logical k-slot at this phys slot
            const u16* gp = g + (long)(r0 + row) * ldg + (k0 + 8 * ls);
            u16* lp = &lds[bufi][arr * 4096 + (vt >> 6) * 512];  // wave-uniform
            gl16(gp, lp);
        }
    };

    // stage fp32 A tile: reg load, split (PREC0: bf16 hi+lo; PREC1: f16 hi),
    // swizzled ds_write
    auto stage_a_f32 = [&](int bufi, const float* g, int ldg, int kk) {
        int r = tid >> 1;
        int hf = (tid & 1) * 16;
        const float* p = g + (long)(m0 + r) * ldg + kk + hf;
        float4 a0 = *(const float4*)(p + 0);
        float4 a1 = *(const float4*)(p + 4);
        float4 a2 = *(const float4*)(p + 8);
        float4 a3 = *(const float4*)(p + 12);
        float fv[16] = {a0.x, a0.y, a0.z, a0.w, a1.x, a1.y, a1.z, a1.w,
                        a2.x, a2.y, a2.z, a2.w, a3.x, a3.y, a3.z, a3.w};
        u16 hb[16], lb[16];
#pragma unroll
        for (int i = 0; i < 16; ++i) {
            if constexpr (PREC == 0)
                split_bf(fv[i], hb[i], lb[i]);
            else
                hb[i] = __builtin_bit_cast(u16, (_Float16)fv[i]);
        }
        int sw = (r >> 1) & 3;
        int ls0 = hf >> 3;  // 0 or 2
        u32x4 h0 = {(u32)hb[0] | ((u32)hb[1] << 16), (u32)hb[2] | ((u32)hb[3] << 16),
                    (u32)hb[4] | ((u32)hb[5] << 16), (u32)hb[6] | ((u32)hb[7] << 16)};
        u32x4 h1 = {(u32)hb[8] | ((u32)hb[9] << 16), (u32)hb[10] | ((u32)hb[11] << 16),
                    (u32)hb[12] | ((u32)hb[13] << 16), (u32)hb[14] | ((u32)hb[15] << 16)};
        u16* ah = &lds[bufi][AH * 4096 + r * 32];
        *(u32x4*)(ah + (((ls0 + 0) ^ sw) << 3)) = h0;
        *(u32x4*)(ah + (((ls0 + 1) ^ sw) << 3)) = h1;
        if constexpr (TERMS == 3) {
            u32x4 l0 = {(u32)lb[0] | ((u32)lb[1] << 16), (u32)lb[2] | ((u32)lb[3] << 16),
                        (u32)lb[4] | ((u32)lb[5] << 16), (u32)lb[6] | ((u32)lb[7] << 16)};
            u32x4 l1 = {(u32)lb[8] | ((u32)lb[9] << 16), (u32)lb[10] | ((u32)lb[11] << 16),
                        (u32)lb[12] | ((u32)lb[13] << 16), (u32)lb[14] | ((u32)lb[15] << 16)};
            u16* al = &lds[bufi][AL * 4096 + r * 32];
            *(u32x4*)(al + (((ls0 + 0) ^ sw) << 3)) = l0;
            *(u32x4*)(al + (((ls0 + 1) ^ sw) << 3)) = l1;
        }
    };

    auto stage = [&](int bufi, int t) {
        int k0 = t * 32;
        stage_gl(bufi, BH, Bhi, n0, ldb, k0);
        if (TERMS == 3) stage_gl(bufi, BL, Blo, n0, ldb, k0);
        if (ASRC == 0) {
            stage_gl(bufi, AH, Ahi, m0, lda, k0);
            if (TERMS == 3) stage_gl(bufi, AL, Alo, m0, lda, k0);
        } else if (ASRC == 1) {
            stage_a_f32(bufi, Af, lda, k0);
        } else {
            if (k0 < HH)
                stage_gl(bufi, AH, Ahi, m0, lda, k0);
            else
                stage_a_f32(bufi, Af, lda, k0 - HH);
        }
    };

    const int NT = K / 32;
    stage(0, 0);
    __syncthreads();
    int cur = 0;
    using FT = typename FragT<PREC>::T;
    for (int t = 0; t < NT; ++t) {
        if (t + 1 < NT) stage(cur ^ 1, t + 1);  // prefetch overlaps compute below

        const u16* L = lds[cur];
        FT afh[4], afl[4], bfh[4], bfl[4];
#pragma unroll
        for (int i = 0; i < 4; ++i) {
            int ra = wm + i * 16 + fr;
            int rb = wn + i * 16 + fr;
            int oa = ra * 32 + ((kq ^ ((ra >> 1) & 3)) << 3);
            int ob = rb * 32 + ((kq ^ ((rb >> 1) & 3)) << 3);
            afh[i] = *(const FT*)(L + AH * 4096 + oa);
            bfh[i] = *(const FT*)(L + BH * 4096 + ob);
            if (TERMS == 3) {
                afl[i] = *(const FT*)(L + AL * 4096 + oa);
                bfl[i] = *(const FT*)(L + BL * 4096 + ob);
            }
        }
#pragma unroll
        for (int i = 0; i < 4; ++i)
#pragma unroll
            for (int j = 0; j < 4; ++j) {
                acc[i][j] = mfma16(afh[i], bfh[j], acc[i][j]);
                if (TERMS == 3) {
                    acc[i][j] = mfma16(afl[i], bfh[j], acc[i][j]);
                    acc[i][j] = mfma16(afh[i], bfl[j], acc[i][j]);
                }
            }
        __syncthreads();  // drains prefetch vmcnt + ds_writes, releases buffers
        cur ^= 1;
    }

    // epilogue: C/D layout col = lane&15, row = (lane>>4)*4 + reg (verified r1)
    long obase = (long)bz * sC + (long)kh * sKh;
    int fq = (lane >> 4) * 4;
#pragma unroll
    for (int i = 0; i < 4; ++i)
#pragma unroll
        for (int j = 0; j < 4; ++j)
#pragma unroll
            for (int g = 0; g < 4; ++g) {
                int row = m0 + wm + i * 16 + fq + g;
                int col = n0 + wn + j * 16 + fr;
                long idx = obase + (long)row * N + col;
                float v = acc[i][j][g];
                if constexpr (EPI == 1) {
                    u16 h2, l2;
                    split_bf(v, h2, l2);
                    Chi[idx] = h2;
                    Clo[idx] = l2;
                } else if constexpr (EPI == 2) {
                    // tanh(x) = 1 - 2/(e^{2x}+1); hw exp + rcp, err ~1e-6
                    float x = v + bias[col];
                    float t2 = __expf(2.f * x);
                    C[idx] = 1.f - 2.f * __builtin_amdgcn_rcpf(t2 + 1.f);
                } else {
                    Chi[idx] = __builtin_bit_cast(u16, (_Float16)v);
                }
            }
}

extern "C" void kernel_launch(void* const* d_in, const int* in_sizes, int n_in,
                              void* d_out, int out_size, void* d_ws, size_t ws_size,
                              hipStream_t stream) {
    const float* ht = (const float*)d_in[0];
    const float* hs = (const float*)d_in[1];
    const int* source = (const int*)d_in[2];
    const float* Wa = (const float*)d_in[3];
    const float* Wc = (const float*)d_in[4];
    const float* bias = (const float*)d_in[5];
    float* out = (float*)d_out;

    char* w = (char*)d_ws;
    size_t off = 0;
    auto alloc = [&](size_t bytes) -> void* {
        void* p = w + off;
        off += (bytes + 255) & ~(size_t)255;
        return p;
    };
    int* lens = (int*)alloc(256);
    u16* keysHi = (u16*)alloc((size_t)BB * TS * HH * 2);  // 16.78 MB (bf16)
    u16* keysLo = (u16*)alloc((size_t)BB * TS * HH * 2);
    // hsR row-major bf16 hi/lo (G1 A). Dead after G1; the split-K score
    // arrays overlay them exactly (2 x 16.78 MB each side).
    u16* hsRHi = (u16*)alloc((size_t)BB * TS * HH * 2);
    u16* hsRLo = (u16*)alloc((size_t)BB * TS * HH * 2);
    u16* hsTHi = (u16*)alloc((size_t)BB * HH * TS * 2);  // 16.78 MB (f16 hi)
    u16* WaTHi = (u16*)alloc((size_t)HH * HH * 2);       // 2.10 MB (bf16)
    u16* WaTLo = (u16*)alloc((size_t)HH * HH * 2);
    // total ~88.1 MB, identical budget to rounds 2-5 (proven).
    // overlays:
    //   scoreH0|scoreH1 -> hsRHi region;  scoreL0|scoreL1 -> hsRLo region
    //   cHi f16 -> keysHi (dead after G2); WcTHi f16 -> scoreL0 (dead after softmax)
    u16* scoreH0 = hsRHi;
    u16* scoreH1 = hsRHi + (size_t)BB * TT * TS;
    u16* scoreL0 = hsRLo;
    u16* scoreL1 = hsRLo + (size_t)BB * TT * TS;
    u16* cHi = keysHi;
    u16* WcTHi = scoreL0;
    u16* prob = scoreH0;  // softmax writes f16 prob in place of scoreH0

    lens_kernel<<<BB, TS, 0, stream>>>(source, lens);
    transpose_split_kernel<0><<<dim3(HH / 32, HH / 32, 1), dim3(32, 8), 0, stream>>>(
        Wa, WaTHi, WaTLo, HH, HH);
    // hs prep: hsR (row-major bf16 split) + hsT (f16, transposed) in one read
    hs_prep_kernel<<<dim3(HH / 32, TS / 32, BB), dim3(32, 8), 0, stream>>>(
        hs, hsRHi, hsRLo, hsTHi);

    // G1: keys = hs @ Wa  (bf16 3-term, A = hsR pre-split -> pure global_load_lds,
    //     XCD-swz) -> split store
    gemm_u<0, 0, 1, 3, 1, true><<<dim3(512), 256, 0, stream>>>(
        hsRHi, hsRLo, nullptr, WaTHi, WaTLo,
        nullptr, keysHi, keysLo, nullptr,
        BB * TS, HH, HH, HH, HH, 0, 0, 0, 0);

    // G2: score[b] = ht[b] @ keys[b]^T  (bf16 3-term, split-K=2 -> 512 blocks)
    gemm_u<0, 1, 1, 3, 2, false><<<dim3(TS / 128, TT / 128, 2 * BB), 256, 0, stream>>>(
        nullptr, nullptr, ht, keysHi, keysLo,
        nullptr, scoreH0, scoreL0, nullptr,
        TT, TS, HH / 2, HH, HH,
        (long)TT * HH, (long)TS * HH, (long)TT * TS, (long)BB * TT * TS);

    softmax_mask_kernel<<<BB * TT, 64, 0, stream>>>(scoreH0, scoreL0, scoreH1, scoreL1, lens);

    // G3: c[b] = prob[b] @ hs[b]  (f16 1-term) -> c f16 hi
    gemm_u<1, 0, 3, 1, 1, false><<<dim3(HH / 128, TT / 128, BB), 256, 0, stream>>>(
        prob, nullptr, nullptr, hsTHi, nullptr,
        nullptr, cHi, nullptr, nullptr,
        TT, HH, TS, TS, TS,
        (long)TT * TS, (long)HH * TS, (long)TT * HH, 0);

    // WcT f16-hi transpose scheduled late to overlay the (dead) scoreL0 buffer
    transpose_split_kernel<1><<<dim3(OO / 32, 2 * HH / 32, 1), dim3(32, 8), 0, stream>>>(
        Wc, WcTHi, nullptr, 2 * HH, OO);

    // G4: out = tanh(concat(c, ht) @ Wc + b)  (f16 1-term, XCD-swz)
    gemm_u<1, 2, 2, 1, 1, true><<<dim3(512), 256, 0, stream>>>(
        cHi, nullptr, ht, WcTHi, nullptr,
        out, nullptr, nullptr, bias,
        BB * TT, OO, 2 * HH, HH, 2 * HH, 0, 0, 0, 0);
}